// Round 3
// baseline (450.131 us; speedup 1.0000x reference)
//
#include <hip/hip_runtime.h>

// ---------------------------------------------------------------------------
// HFLongFormerSelfAttentionBlock — MI355X implementation (round 3)
//
// I/O is FLOAT32 (per the reference); internal compute uses bf16 MFMA with
// fp32 accumulation/epilogues (tolerance is bf16-grade: 2% of max|ref|).
//
// Structural simplifications vs the JAX reference (all exact):
//  * global-query branch (wqg..bvg) only affects attn[:, -1] (pos 2303) which
//    is dropped by [:, :s0] -> skipped entirely.
//  * padded rows (2048..2303) never reach the output; padded keys get prob 0;
//    the "global" key/value k[:,-1]/v[:,-1] equal bk/bv (biases), folded into
//    the softmax as one extra column per head.
// ---------------------------------------------------------------------------

using bf16x8 = __attribute__((ext_vector_type(8))) short;
using bf16x4 = __attribute__((ext_vector_type(4))) short;
using f32x4  = __attribute__((ext_vector_type(4))) float;

__device__ __forceinline__ float b2f(short s) {
    return __uint_as_float(((unsigned int)(unsigned short)s) << 16);
}
__device__ __forceinline__ short f2b(float f) {
    unsigned int u = __float_as_uint(f);
    u += 0x7fffu + ((u >> 16) & 1u);   // round-to-nearest-even
    return (short)(u >> 16);
}
__device__ __forceinline__ f32x4 mfma16(bf16x8 a, bf16x8 b, f32x4 c) {
    return __builtin_amdgcn_mfma_f32_16x16x32_bf16(a, b, c, 0, 0, 0);
}
// exp with argument forced <= 0 (softmax args are always <= 0 here).
__device__ __forceinline__ float safe_exp(float x) {
    return expf((x <= 0.f) ? x : 0.f);
}
#define NEGF (-3.0e38f)

// ---------------------------------------------------------------------------
// fp32 -> bf16 elementwise convert (n multiple of 1024). grid n/1024, 256 thr
// ---------------------------------------------------------------------------
__global__ void cvt_f32_bf16(const float* __restrict__ in, short* __restrict__ out, int n) {
    int i = (blockIdx.x * 256 + threadIdx.x) * 4;
    f32x4 v = *(const f32x4*)(in + i);
    bf16x4 o;
#pragma unroll
    for (int j = 0; j < 4; ++j) o[j] = f2b(v[j]);
    *(bf16x4*)(out + i) = o;
}

// ---------------------------------------------------------------------------
// fp32 in, bf16 transposed out: out[c][r] = in[r][c], in is R x C.
// grid (C/32, R/32), block (32,8)
// ---------------------------------------------------------------------------
__global__ void cvt_transpose(const float* __restrict__ in, short* __restrict__ out,
                              int R, int C) {
    __shared__ short tile[32][33];
    int bx = blockIdx.x * 32, by = blockIdx.y * 32;
    int tx = threadIdx.x, ty = threadIdx.y;
    for (int i = ty; i < 32; i += 8)
        tile[i][tx] = f2b(in[(size_t)(by + i) * C + bx + tx]);
    __syncthreads();
    for (int i = ty; i < 32; i += 8)
        out[(size_t)(bx + i) * R + by + tx] = tile[tx][i];
}

// V (b,s,h,d) bf16 -> Vt (b,h,d,s) bf16.  grid (2048/32, 64/32, B*NH), block (32,8)
__global__ void transpose_v(const short* __restrict__ V, short* __restrict__ Vt) {
    __shared__ short tile[32][33];
    int bh = blockIdx.z; int b = bh >> 4, h = bh & 15;
    int j0 = blockIdx.x * 32, d0 = blockIdx.y * 32;
    int tx = threadIdx.x, ty = threadIdx.y;
    const short* src = V + (size_t)b * 2048 * 1024 + h * 64;
    for (int i = ty; i < 32; i += 8)
        tile[i][tx] = src[(size_t)(j0 + i) * 1024 + d0 + tx];
    __syncthreads();
    short* dst = Vt + ((size_t)bh * 64 + d0) * 2048 + j0;
    for (int i = ty; i < 32; i += 8)
        dst[(size_t)i * 2048 + tx] = tile[tx][i];
}

// ---------------------------------------------------------------------------
// GEMM: acc(MxN) = A(MxK) @ B, Bt = B^T (NxK), bf16 in, fp32 acc.
// mode 0: C   = bf16((acc+bias)*scale)
// mode 1: C   = bf16(gelu(acc+bias))
// mode 2: Cf  = acc+bias+resf   (fp32 out, fp32 residual)
// 128x128 tile, BK=32, 4 waves of 64x64.
// ---------------------------------------------------------------------------
__global__ __launch_bounds__(256, 2) void gemm_bt(
    const short* __restrict__ A, const short* __restrict__ Bt,
    const float* __restrict__ bias, const float* __restrict__ resf,
    short* __restrict__ C, float* __restrict__ Cf,
    int M, int N, int K, float scale, int mode)
{
    __shared__ short As[128 * 40];
    __shared__ short Bs[128 * 40];
    int m0 = blockIdx.x * 128, n0 = blockIdx.y * 128;
    int t = threadIdx.x;
    int wave = t >> 6, lane = t & 63, quad = lane >> 4, l16 = lane & 15;
    int wr = (wave >> 1) * 64, wc = (wave & 1) * 64;

    f32x4 acc[4][4] = {};
    for (int k0 = 0; k0 < K; k0 += 32) {
#pragma unroll
        for (int l = 0; l < 2; ++l) {
            int idx = l * 256 + t;
            int row = idx >> 2, kc = (idx & 3) * 8;
            *(bf16x8*)(As + row * 40 + kc) = *(const bf16x8*)(A  + (size_t)(m0 + row) * K + k0 + kc);
            *(bf16x8*)(Bs + row * 40 + kc) = *(const bf16x8*)(Bt + (size_t)(n0 + row) * K + k0 + kc);
        }
        __syncthreads();
        bf16x8 af[4], bfr[4];
#pragma unroll
        for (int i = 0; i < 4; ++i)
            af[i] = *(bf16x8*)(As + (wr + i * 16 + l16) * 40 + quad * 8);
#pragma unroll
        for (int j = 0; j < 4; ++j)
            bfr[j] = *(bf16x8*)(Bs + (wc + j * 16 + l16) * 40 + quad * 8);
#pragma unroll
        for (int i = 0; i < 4; ++i)
#pragma unroll
            for (int j = 0; j < 4; ++j)
                acc[i][j] = mfma16(af[i], bfr[j], acc[i][j]);
        __syncthreads();
    }
#pragma unroll
    for (int j = 0; j < 4; ++j) {
        int col = n0 + wc + j * 16 + l16;
        float bs = bias[col];
#pragma unroll
        for (int i = 0; i < 4; ++i) {
#pragma unroll
            for (int r = 0; r < 4; ++r) {
                int row = m0 + wr + i * 16 + quad * 4 + r;
                float v = acc[i][j][r] + bs;
                if (mode == 0) {
                    C[(size_t)row * N + col] = f2b(v * scale);
                } else if (mode == 1) {
                    v = 0.5f * v * (1.0f + erff(v * 0.70710678118f));
                    C[(size_t)row * N + col] = f2b(v);
                } else {
                    Cf[(size_t)row * N + col] = v + resf[(size_t)row * N + col];
                }
            }
        }
    }
}

// ---------------------------------------------------------------------------
// Windowed attention with global column. One block per (b,h,c): 128 queries,
// 2..3 128-key tiles, flash-style online softmax (finite sentinels),
// PV via LDS round-trip. Q,K,Vt bf16; bk,bv fp32; attn out bf16.
// LDS layout (dynamic, 53760 B):
//   [0 .. 34816)       Ps [128][136]  (aliased as Qs [128][72] at start)
//   [34816 .. 53248)   Ks [128][72]   (aliased as VsT [64][136])
//   [53248 .. 53504)   gkf float[64] ; [53504 .. 53760) gvf float[64]
// ---------------------------------------------------------------------------
__global__ __launch_bounds__(256, 2) void attn_kernel(
    const short* __restrict__ Q, const short* __restrict__ K,
    const short* __restrict__ Vt, const int* __restrict__ mask,
    const float* __restrict__ bk, const float* __restrict__ bv,
    short* __restrict__ attn)
{
    extern __shared__ char smem[];
    short* PsQ = (short*)smem;
    short* KV  = (short*)(smem + 34816);
    float* gkf = (float*)(smem + 53248);
    float* gvf = (float*)(smem + 53504);

    int blk = blockIdx.x;
    int c = blk & 15, h = (blk >> 4) & 15, b = blk >> 8;
    int t = threadIdx.x;
    int wave = t >> 6, lane = t & 63, quad = lane >> 4, l16 = lane & 15;
    int q0 = c * 128;
    const int bs_off = b * 2048;

    // stage Q tile (128 x 64) into PsQ-as-Qs (stride 72)
#pragma unroll
    for (int l = 0; l < 4; ++l) {
        int idx = l * 256 + t;
        int p = idx >> 3, dc = (idx & 7) * 8;
        *(bf16x8*)(PsQ + p * 72 + dc) =
            *(const bf16x8*)(Q + ((size_t)(bs_off + q0 + p)) * 1024 + h * 64 + dc);
    }
    if (t < 64) { gkf[t] = bk[h * 64 + t]; gvf[t] = bv[h * 64 + t]; }
    __syncthreads();

    // preload Q A-frags (rows wave*32..+31)
    bf16x8 aq[2][2];
#pragma unroll
    for (int ti = 0; ti < 2; ++ti)
#pragma unroll
        for (int ks = 0; ks < 2; ++ks)
            aq[ti][ks] = *(bf16x8*)(PsQ + (wave * 32 + ti * 16 + l16) * 72 + ks * 32 + quad * 8);

    // global-column scores s_g[i] = q_i . bk  (scalar LDS dot + xor-reduce)
    float s_g[2][4];
#pragma unroll
    for (int ti = 0; ti < 2; ++ti)
#pragma unroll
        for (int r = 0; r < 4; ++r) {
            int row = wave * 32 + ti * 16 + quad * 4 + r;
            float part = 0.f;
#pragma unroll
            for (int dd = 0; dd < 4; ++dd) {
                int d = l16 * 4 + dd;
                part += b2f(PsQ[row * 72 + d]) * gkf[d];
            }
#pragma unroll
            for (int dsh = 1; dsh < 16; dsh <<= 1) part += __shfl_xor(part, dsh);
            s_g[ti][r] = part;
        }

    f32x4 o_acc[2][4] = {};
    float m_run[2][4], l_run[2][4];
#pragma unroll
    for (int ti = 0; ti < 2; ++ti)
#pragma unroll
        for (int r = 0; r < 4; ++r) { m_run[ti][r] = NEGF; l_run[ti][r] = 0.f; }

    int kt_beg = (q0 == 0) ? 1 : 0;
    int kt_end = (q0 + 256 > 2048) ? 2 : 3;
    for (int kt = kt_beg; kt < kt_end; ++kt) {
        int jb = q0 + (kt - 1) * 128;
        __syncthreads();                 // prior VsT/Qs reads complete
        // stage K tile (128 x 64), stride 72
#pragma unroll
        for (int l = 0; l < 4; ++l) {
            int idx = l * 256 + t;
            int p = idx >> 3, dc = (idx & 7) * 8;
            *(bf16x8*)(KV + p * 72 + dc) =
                *(const bf16x8*)(K + ((size_t)(bs_off + jb + p)) * 1024 + h * 64 + dc);
        }
        __syncthreads();

        // S = Q K^T  (wave: 32 q-rows x 128 keys)
        f32x4 s_acc[2][8] = {};
#pragma unroll
        for (int ks = 0; ks < 2; ++ks) {
            bf16x8 bk8[8];
#pragma unroll
            for (int tj = 0; tj < 8; ++tj)
                bk8[tj] = *(bf16x8*)(KV + (tj * 16 + l16) * 72 + ks * 32 + quad * 8);
#pragma unroll
            for (int ti = 0; ti < 2; ++ti)
#pragma unroll
                for (int tj = 0; tj < 8; ++tj)
                    s_acc[ti][tj] = mfma16(aq[ti][ks], bk8[tj], s_acc[ti][tj]);
        }

        // band mask (|j-i|<=128), key mask, tile row max — all finite
        float negj[8]; int jcol[8];
#pragma unroll
        for (int tj = 0; tj < 8; ++tj) {
            jcol[tj] = jb + tj * 16 + l16;
            negj[tj] = (mask[bs_off + jcol[tj]] != 0) ? NEGF : 0.f;
        }
        float tmax[2][4];
#pragma unroll
        for (int ti = 0; ti < 2; ++ti)
#pragma unroll
            for (int r = 0; r < 4; ++r) tmax[ti][r] = NEGF;
#pragma unroll
        for (int ti = 0; ti < 2; ++ti) {
            int irow_base = q0 + wave * 32 + ti * 16 + quad * 4;
#pragma unroll
            for (int tj = 0; tj < 8; ++tj)
#pragma unroll
                for (int r = 0; r < 4; ++r) {
                    int dj = jcol[tj] - (irow_base + r);
                    float sc = (dj >= -128 && dj <= 128) ? (s_acc[ti][tj][r] + negj[tj]) : NEGF;
                    s_acc[ti][tj][r] = sc;
                    tmax[ti][r] = fmaxf(tmax[ti][r], sc);
                }
        }
#pragma unroll
        for (int ti = 0; ti < 2; ++ti)
#pragma unroll
            for (int r = 0; r < 4; ++r)
#pragma unroll
                for (int dsh = 1; dsh < 16; dsh <<= 1)
                    tmax[ti][r] = fmaxf(tmax[ti][r], __shfl_xor(tmax[ti][r], dsh));

        float alpha[2][4], lsum[2][4];
#pragma unroll
        for (int ti = 0; ti < 2; ++ti)
#pragma unroll
            for (int r = 0; r < 4; ++r) {
                float mnew = fmaxf(m_run[ti][r], tmax[ti][r]);
                alpha[ti][r] = safe_exp(m_run[ti][r] - mnew);
                m_run[ti][r] = mnew;
                lsum[ti][r] = 0.f;
            }
        // P = exp(S - m), write to Ps [q][key] (stride 136)
#pragma unroll
        for (int ti = 0; ti < 2; ++ti)
#pragma unroll
            for (int tj = 0; tj < 8; ++tj)
#pragma unroll
                for (int r = 0; r < 4; ++r) {
                    float p = safe_exp(s_acc[ti][tj][r] - m_run[ti][r]);
                    lsum[ti][r] += p;
                    PsQ[(wave * 32 + ti * 16 + quad * 4 + r) * 136 + tj * 16 + l16] = f2b(p);
                }
#pragma unroll
        for (int ti = 0; ti < 2; ++ti)
#pragma unroll
            for (int r = 0; r < 4; ++r) {
#pragma unroll
                for (int dsh = 1; dsh < 16; dsh <<= 1) lsum[ti][r] += __shfl_xor(lsum[ti][r], dsh);
                l_run[ti][r] = l_run[ti][r] * alpha[ti][r] + lsum[ti][r];
            }
#pragma unroll
        for (int ti = 0; ti < 2; ++ti)
#pragma unroll
            for (int dj = 0; dj < 4; ++dj)
#pragma unroll
                for (int r = 0; r < 4; ++r) o_acc[ti][dj][r] *= alpha[ti][r];

        __syncthreads();                 // all waves done with Ks
        // stage V^T tile (64 d x 128 keys), stride 136, from Vt (coalesced)
#pragma unroll
        for (int l = 0; l < 4; ++l) {
            int idx = l * 256 + t;
            int d = idx >> 4, kc = (idx & 15) * 8;
            *(bf16x8*)(KV + d * 136 + kc) =
                *(const bf16x8*)(Vt + ((size_t)(b * 16 + h) * 64 + d) * 2048 + jb + kc);
        }
        __syncthreads();
        // O += P V
#pragma unroll
        for (int ks = 0; ks < 4; ++ks) {
            bf16x8 ap[2], bv8[4];
#pragma unroll
            for (int ti = 0; ti < 2; ++ti)
                ap[ti] = *(bf16x8*)(PsQ + (wave * 32 + ti * 16 + l16) * 136 + ks * 32 + quad * 8);
#pragma unroll
            for (int dj = 0; dj < 4; ++dj)
                bv8[dj] = *(bf16x8*)(KV + (dj * 16 + l16) * 136 + ks * 32 + quad * 8);
#pragma unroll
            for (int ti = 0; ti < 2; ++ti)
#pragma unroll
                for (int dj = 0; dj < 4; ++dj)
                    o_acc[ti][dj] = mfma16(ap[ti], bv8[dj], o_acc[ti][dj]);
        }
    }

    // epilogue: fold in global column (k=bk, v=bv), normalize, query-mask, store
#pragma unroll
    for (int ti = 0; ti < 2; ++ti) {
        int irow_base = q0 + wave * 32 + ti * 16 + quad * 4;
#pragma unroll
        for (int r = 0; r < 4; ++r) {
            int i = irow_base + r;
            float m2 = fmaxf(m_run[ti][r], s_g[ti][r]);
            float pg = safe_exp(s_g[ti][r] - m2);
            float al = safe_exp(m_run[ti][r] - m2);
            float l2 = l_run[ti][r] * al + pg;
            float invl = 1.f / fmaxf(l2, 1e-30f);
            float qm = (mask[bs_off + i] > 0) ? 0.f : 1.f;
#pragma unroll
            for (int dj = 0; dj < 4; ++dj) {
                int d = dj * 16 + l16;
                float val = (o_acc[ti][dj][r] * al + pg * gvf[d]) * invl * qm;
                attn[((size_t)(bs_off + i)) * 1024 + h * 64 + d] = f2b(val);
            }
        }
    }
}

// ---------------------------------------------------------------------------
// y = LN(x + attn) * g + b ; writes bf16 (GEMM input) AND fp32 (residual).
// x fp32, attn bf16, g/b fp32. One block per row, H=1024.
// ---------------------------------------------------------------------------
__global__ __launch_bounds__(256) void resid_ln(
    const float* __restrict__ x, const short* __restrict__ attn,
    const float* __restrict__ g, const float* __restrict__ be,
    short* __restrict__ yb, float* __restrict__ yf)
{
    int row = blockIdx.x, t = threadIdx.x;
    int lane = t & 63, wave = t >> 6;
    const size_t base = (size_t)row * 1024;
    float v[4]; float s = 0.f, s2 = 0.f;
#pragma unroll
    for (int i = 0; i < 4; ++i) {
        int c = i * 256 + t;
        float val = x[base + c] + b2f(attn[base + c]);
        v[i] = val; s += val; s2 += val * val;
    }
#pragma unroll
    for (int off = 32; off > 0; off >>= 1) { s += __shfl_xor(s, off); s2 += __shfl_xor(s2, off); }
    __shared__ float red[8];
    if (lane == 0) { red[wave] = s; red[4 + wave] = s2; }
    __syncthreads();
    s  = red[0] + red[1] + red[2] + red[3];
    s2 = red[4] + red[5] + red[6] + red[7];
    float mu  = s * (1.f / 1024.f);
    float var = s2 * (1.f / 1024.f) - mu * mu;
    float inv = rsqrtf(fmaxf(var, 0.f) + 1e-5f);
#pragma unroll
    for (int i = 0; i < 4; ++i) {
        int c = i * 256 + t;
        float o = (v[i] - mu) * inv * g[c] + be[c];
        yb[base + c] = f2b(o);
        yf[base + c] = o;
    }
}

// ---------------------------------------------------------------------------
// workspace layout, units = bf16 elements (2 B). fp32 arrays take 2x units.
// total 47M units = 94 MB.
// ---------------------------------------------------------------------------
static constexpr size_t MEG     = 1048576;
static constexpr size_t OFF_WQT = 0;            // 1M
static constexpr size_t OFF_WKT = 1 * MEG;      // 1M
static constexpr size_t OFF_WVT = 2 * MEG;      // 1M
static constexpr size_t OFF_W1T = 3 * MEG;      // 4M
static constexpr size_t OFF_W2T = 7 * MEG;      // 4M
static constexpr size_t OFF_XB  = 11 * MEG;     // 4M
static constexpr size_t OFF_Q   = 15 * MEG;     // 4M
static constexpr size_t OFF_K   = 19 * MEG;     // 4M
static constexpr size_t OFF_V   = 23 * MEG;     // 4M
static constexpr size_t OFF_VT  = 27 * MEG;     // 4M
static constexpr size_t OFF_ATT = 31 * MEG;     // 4M
static constexpr size_t OFF_YN  = 35 * MEG;     // 4M (bf16)
static constexpr size_t OFF_YF  = 39 * MEG;     // 8M units = 4M fp32
static constexpr size_t OFF_H   = OFF_Q;        // 16M, aliases Q..VT (dead)

extern "C" void kernel_launch(void* const* d_in, const int* in_sizes, int n_in,
                              void* d_out, int out_size, void* d_ws, size_t ws_size,
                              hipStream_t stream) {
    (void)in_sizes; (void)n_in; (void)out_size; (void)ws_size;
    const float* x    = (const float*)d_in[0];
    const int*   mask = (const int*)  d_in[1];
    const float* wq   = (const float*)d_in[2];
    const float* bq   = (const float*)d_in[3];
    const float* wk   = (const float*)d_in[4];
    const float* bk   = (const float*)d_in[5];
    const float* wv   = (const float*)d_in[6];
    const float* bv   = (const float*)d_in[7];
    // d_in[8..13] (global-query branch) are provably dead for the output
    const float* lng  = (const float*)d_in[14];
    const float* lnb  = (const float*)d_in[15];
    const float* w1   = (const float*)d_in[16];
    const float* b1   = (const float*)d_in[17];
    const float* w2   = (const float*)d_in[18];
    const float* b2   = (const float*)d_in[19];
    short* ws  = (short*)d_ws;
    float* out = (float*)d_out;

    dim3 tb(32, 8);
    cvt_transpose<<<dim3(32, 32),  tb, 0, stream>>>(wq, ws + OFF_WQT, 1024, 1024);
    cvt_transpose<<<dim3(32, 32),  tb, 0, stream>>>(wk, ws + OFF_WKT, 1024, 1024);
    cvt_transpose<<<dim3(32, 32),  tb, 0, stream>>>(wv, ws + OFF_WVT, 1024, 1024);
    cvt_transpose<<<dim3(128, 32), tb, 0, stream>>>(w1, ws + OFF_W1T, 1024, 4096);
    cvt_transpose<<<dim3(32, 128), tb, 0, stream>>>(w2, ws + OFF_W2T, 4096, 1024);
    cvt_f32_bf16<<<4096, 256, 0, stream>>>(x, ws + OFF_XB, 4194304);

    // Q = (x@wq + bq)/8 ; K = x@wk + bk ; V = x@wv + bv   (bf16 out)
    gemm_bt<<<dim3(32, 8), 256, 0, stream>>>(ws + OFF_XB, ws + OFF_WQT, bq, nullptr,
                                             ws + OFF_Q, nullptr, 4096, 1024, 1024, 0.125f, 0);
    gemm_bt<<<dim3(32, 8), 256, 0, stream>>>(ws + OFF_XB, ws + OFF_WKT, bk, nullptr,
                                             ws + OFF_K, nullptr, 4096, 1024, 1024, 1.0f, 0);
    gemm_bt<<<dim3(32, 8), 256, 0, stream>>>(ws + OFF_XB, ws + OFF_WVT, bv, nullptr,
                                             ws + OFF_V, nullptr, 4096, 1024, 1024, 1.0f, 0);
    transpose_v<<<dim3(64, 2, 32), tb, 0, stream>>>(ws + OFF_V, ws + OFF_VT);

    attn_kernel<<<512, 256, 53760, stream>>>(ws + OFF_Q, ws + OFF_K, ws + OFF_VT,
                                             mask, bk, bv, ws + OFF_ATT);

    resid_ln<<<4096, 256, 0, stream>>>(x, ws + OFF_ATT, lng, lnb,
                                       ws + OFF_YN, (float*)(ws + OFF_YF));

    // h = gelu(y@w1 + b1) ; out = y + h@w2 + b2  (final out fp32)
    gemm_bt<<<dim3(32, 32), 256, 0, stream>>>(ws + OFF_YN, ws + OFF_W1T, b1, nullptr,
                                              ws + OFF_H, nullptr, 4096, 4096, 1024, 1.0f, 1);
    gemm_bt<<<dim3(32, 8), 256, 0, stream>>>(ws + OFF_H, ws + OFF_W2T, b2,
                                             (const float*)(ws + OFF_YF),
                                             nullptr, out, 4096, 1024, 4096, 1.0f, 2);
}

// Round 4
// 394.637 us; speedup vs baseline: 1.1406x; 1.1406x over previous
//
#include <hip/hip_runtime.h>

// ---------------------------------------------------------------------------
// HFLongFormerSelfAttentionBlock — MI355X implementation (round 4)
//
// I/O fp32; internal bf16 MFMA, fp32 accumulation/epilogues.
// Round-4: m97-style GEMM (global_load_lds width=16, unpadded LDS), fused QKV
// GEMM (N=3072), merged weight-transpose dispatch.
// ---------------------------------------------------------------------------

using bf16x8 = __attribute__((ext_vector_type(8))) short;
using bf16x4 = __attribute__((ext_vector_type(4))) short;
using f32x4  = __attribute__((ext_vector_type(4))) float;

__device__ __forceinline__ float b2f(short s) {
    return __uint_as_float(((unsigned int)(unsigned short)s) << 16);
}
__device__ __forceinline__ short f2b(float f) {
    unsigned int u = __float_as_uint(f);
    u += 0x7fffu + ((u >> 16) & 1u);   // round-to-nearest-even
    return (short)(u >> 16);
}
__device__ __forceinline__ f32x4 mfma16(bf16x8 a, bf16x8 b, f32x4 c) {
    return __builtin_amdgcn_mfma_f32_16x16x32_bf16(a, b, c, 0, 0, 0);
}
__device__ __forceinline__ float safe_exp(float x) {
    return expf((x <= 0.f) ? x : 0.f);
}
// async global->LDS, 16 B per lane; LDS dest = wave-uniform base + lane*16
__device__ __forceinline__ void load_lds16(const short* g, short* l) {
    __builtin_amdgcn_global_load_lds((const __attribute__((address_space(1))) void*)g,
                                     (__attribute__((address_space(3))) void*)l, 16, 0, 0);
}
#define NEGF (-3.0e38f)

// ---------------------------------------------------------------------------
// fp32 -> bf16 elementwise convert (n multiple of 1024). grid n/1024, 256 thr
// ---------------------------------------------------------------------------
__global__ void cvt_f32_bf16(const float* __restrict__ in, short* __restrict__ out, int n) {
    int i = (blockIdx.x * 256 + threadIdx.x) * 4;
    f32x4 v = *(const f32x4*)(in + i);
    bf16x4 o;
#pragma unroll
    for (int j = 0; j < 4; ++j) o[j] = f2b(v[j]);
    *(bf16x4*)(out + i) = o;
}

// ---------------------------------------------------------------------------
// fp32 in, bf16 transposed out: out[c][r] = in[r][c], in is R x C.
// grid (C/32, R/32), block (32,8)
// ---------------------------------------------------------------------------
__global__ void cvt_transpose(const float* __restrict__ in, short* __restrict__ out,
                              int R, int C) {
    __shared__ short tile[32][33];
    int bx = blockIdx.x * 32, by = blockIdx.y * 32;
    int tx = threadIdx.x, ty = threadIdx.y;
    for (int i = ty; i < 32; i += 8)
        tile[i][tx] = f2b(in[(size_t)(by + i) * C + bx + tx]);
    __syncthreads();
    for (int i = ty; i < 32; i += 8)
        out[(size_t)(bx + i) * R + by + tx] = tile[tx][i];
}

// wq/wk/wv (each 1024x1024 fp32) -> WQKVT (3072x1024 bf16, = [wq^T;wk^T;wv^T])
// grid (32, 32, 3), block (32,8)
__global__ void cvt_transpose_qkv(const float* __restrict__ wq, const float* __restrict__ wk,
                                  const float* __restrict__ wv, short* __restrict__ out) {
    __shared__ short tile[32][33];
    const float* in = (blockIdx.z == 0) ? wq : (blockIdx.z == 1) ? wk : wv;
    short* dst = out + (size_t)blockIdx.z * 1024 * 1024;
    int bx = blockIdx.x * 32, by = blockIdx.y * 32;
    int tx = threadIdx.x, ty = threadIdx.y;
    for (int i = ty; i < 32; i += 8)
        tile[i][tx] = f2b(in[(size_t)(by + i) * 1024 + bx + tx]);
    __syncthreads();
    for (int i = ty; i < 32; i += 8)
        dst[(size_t)(bx + i) * 1024 + by + tx] = tile[tx][i];
}

// V columns of QKV (b,s,3072)[,2048+h*64+d] -> Vt (b,h,d,s).
// grid (2048/32, 64/32, B*NH), block (32,8)
__global__ void transpose_v(const short* __restrict__ QKV, short* __restrict__ Vt) {
    __shared__ short tile[32][33];
    int bh = blockIdx.z; int b = bh >> 4, h = bh & 15;
    int j0 = blockIdx.x * 32, d0 = blockIdx.y * 32;
    int tx = threadIdx.x, ty = threadIdx.y;
    const short* src = QKV + (size_t)b * 2048 * 3072 + 2048 + h * 64;
    for (int i = ty; i < 32; i += 8)
        tile[i][tx] = src[(size_t)(j0 + i) * 3072 + d0 + tx];
    __syncthreads();
    short* dst = Vt + ((size_t)bh * 64 + d0) * 2048 + j0;
    for (int i = ty; i < 32; i += 8)
        dst[(size_t)i * 2048 + tx] = tile[tx][i];
}

// ---------------------------------------------------------------------------
// GEMM (m97 structure): acc(MxN) = A(MxK) @ B, Bt = B^T (NxK), bf16 in,
// fp32 acc, global_load_lds width-16 staging into unpadded 128x32 LDS tiles.
// mode 0: C = bf16((acc+bias_sel)*scale_sel)   (QKV: bias/scale select by col>>10)
// mode 1: C = bf16(gelu(acc+bias))
// mode 2: Cf = acc+bias+resf                    (fp32 out + fp32 residual)
// ---------------------------------------------------------------------------
__global__ __launch_bounds__(256, 2) void gemm_bt(
    const short* __restrict__ A, const short* __restrict__ Bt,
    const float* __restrict__ bias0, const float* __restrict__ bias1,
    const float* __restrict__ bias2, const float* __restrict__ resf,
    short* __restrict__ C, float* __restrict__ Cf,
    int M, int N, int K, float scale, int scale_cols, int mode)
{
    __shared__ short As[128 * 32];
    __shared__ short Bs[128 * 32];
    int m0 = blockIdx.x * 128, n0 = blockIdx.y * 128;
    int t = threadIdx.x;
    int wave = t >> 6, lane = t & 63, quad = lane >> 4, l16 = lane & 15;
    int wr = (wave >> 1) * 64, wc = (wave & 1) * 64;

    // staging: chunk = (l*4+wave)*64 + lane ; row=chunk>>2 ; kc=(chunk&3)*8
    int ch0 = wave * 64 + lane;            // l = 0
    int ch1 = (4 + wave) * 64 + lane;      // l = 1
    int r0 = ch0 >> 2, kc0 = (ch0 & 3) * 8;
    int r1 = ch1 >> 2, kc1 = (ch1 & 3) * 8;
    const short* a0 = A  + (size_t)(m0 + r0) * K + kc0;
    const short* a1 = A  + (size_t)(m0 + r1) * K + kc1;
    const short* b0 = Bt + (size_t)(n0 + r0) * K + kc0;
    const short* b1 = Bt + (size_t)(n0 + r1) * K + kc1;
    short* lA0 = As + wave * 512;
    short* lA1 = As + (4 + wave) * 512;
    short* lB0 = Bs + wave * 512;
    short* lB1 = Bs + (4 + wave) * 512;

    f32x4 acc[4][4] = {};
    for (int k0 = 0; k0 < K; k0 += 32) {
        load_lds16(a0 + k0, lA0);
        load_lds16(a1 + k0, lA1);
        load_lds16(b0 + k0, lB0);
        load_lds16(b1 + k0, lB1);
        __syncthreads();                    // drains vmcnt before barrier
        bf16x8 af[4], bfr[4];
#pragma unroll
        for (int i = 0; i < 4; ++i)
            af[i] = *(bf16x8*)(As + (wr + i * 16 + l16) * 32 + quad * 8);
#pragma unroll
        for (int j = 0; j < 4; ++j)
            bfr[j] = *(bf16x8*)(Bs + (wc + j * 16 + l16) * 32 + quad * 8);
#pragma unroll
        for (int i = 0; i < 4; ++i)
#pragma unroll
            for (int j = 0; j < 4; ++j)
                acc[i][j] = mfma16(af[i], bfr[j], acc[i][j]);
        __syncthreads();
    }
#pragma unroll
    for (int j = 0; j < 4; ++j) {
        int col = n0 + wc + j * 16 + l16;
        int seg = col >> 10;
        const float* bp = (seg == 0) ? bias0 : (seg == 1) ? bias1 : bias2;
        float bs = bp[col & 1023];
        float sc = (col < scale_cols) ? scale : 1.0f;
#pragma unroll
        for (int i = 0; i < 4; ++i) {
#pragma unroll
            for (int r = 0; r < 4; ++r) {
                int row = m0 + wr + i * 16 + quad * 4 + r;
                float v = acc[i][j][r] + bs;
                if (mode == 0) {
                    C[(size_t)row * N + col] = f2b(v * sc);
                } else if (mode == 1) {
                    v = 0.5f * v * (1.0f + erff(v * 0.70710678118f));
                    C[(size_t)row * N + col] = f2b(v);
                } else {
                    Cf[(size_t)row * N + col] = v + resf[(size_t)row * N + col];
                }
            }
        }
    }
}

// ---------------------------------------------------------------------------
// Windowed attention with global column. One block per (b,h,c): 128 queries,
// 2..3 128-key tiles, flash-style online softmax, PV via LDS round-trip.
// Q/K read from fused QKV buffer (row stride 3072).
// LDS: [0..34816) Ps[128][136] (alias Qs[128][72]); [34816..53248) Ks[128][72]
//      (alias VsT[64][136]); [53248..53504) gkf f32[64]; [53504..) gvf f32[64]
// ---------------------------------------------------------------------------
__global__ __launch_bounds__(256, 2) void attn_kernel(
    const short* __restrict__ QKV, const short* __restrict__ Vt,
    const int* __restrict__ mask,
    const float* __restrict__ bk, const float* __restrict__ bv,
    short* __restrict__ attn)
{
    extern __shared__ char smem[];
    short* PsQ = (short*)smem;
    short* KV  = (short*)(smem + 34816);
    float* gkf = (float*)(smem + 53248);
    float* gvf = (float*)(smem + 53504);

    int blk = blockIdx.x;
    int c = blk & 15, h = (blk >> 4) & 15, b = blk >> 8;
    int t = threadIdx.x;
    int wave = t >> 6, lane = t & 63, quad = lane >> 4, l16 = lane & 15;
    int q0 = c * 128;
    const int bs_off = b * 2048;
    const short* Q = QKV + h * 64;           // col block of fused buffer
    const short* K = QKV + 1024 + h * 64;

    // stage Q tile (128 x 64) into PsQ-as-Qs (stride 72)
#pragma unroll
    for (int l = 0; l < 4; ++l) {
        int idx = l * 256 + t;
        int p = idx >> 3, dc = (idx & 7) * 8;
        *(bf16x8*)(PsQ + p * 72 + dc) =
            *(const bf16x8*)(Q + ((size_t)(bs_off + q0 + p)) * 3072 + dc);
    }
    if (t < 64) { gkf[t] = bk[h * 64 + t]; gvf[t] = bv[h * 64 + t]; }
    __syncthreads();

    bf16x8 aq[2][2];
#pragma unroll
    for (int ti = 0; ti < 2; ++ti)
#pragma unroll
        for (int ks = 0; ks < 2; ++ks)
            aq[ti][ks] = *(bf16x8*)(PsQ + (wave * 32 + ti * 16 + l16) * 72 + ks * 32 + quad * 8);

    // s_g[i] = q_i . bk  (scalar LDS dot + xor-reduce)
    float s_g[2][4];
#pragma unroll
    for (int ti = 0; ti < 2; ++ti)
#pragma unroll
        for (int r = 0; r < 4; ++r) {
            int row = wave * 32 + ti * 16 + quad * 4 + r;
            float part = 0.f;
#pragma unroll
            for (int dd = 0; dd < 4; ++dd) {
                int d = l16 * 4 + dd;
                part += b2f(PsQ[row * 72 + d]) * gkf[d];
            }
#pragma unroll
            for (int dsh = 1; dsh < 16; dsh <<= 1) part += __shfl_xor(part, dsh);
            s_g[ti][r] = part;
        }

    f32x4 o_acc[2][4] = {};
    float m_run[2][4], l_run[2][4];
#pragma unroll
    for (int ti = 0; ti < 2; ++ti)
#pragma unroll
        for (int r = 0; r < 4; ++r) { m_run[ti][r] = NEGF; l_run[ti][r] = 0.f; }

    int kt_beg = (q0 == 0) ? 1 : 0;
    int kt_end = (q0 + 256 > 2048) ? 2 : 3;
    for (int kt = kt_beg; kt < kt_end; ++kt) {
        int jb = q0 + (kt - 1) * 128;
        __syncthreads();
#pragma unroll
        for (int l = 0; l < 4; ++l) {
            int idx = l * 256 + t;
            int p = idx >> 3, dc = (idx & 7) * 8;
            *(bf16x8*)(KV + p * 72 + dc) =
                *(const bf16x8*)(K + ((size_t)(bs_off + jb + p)) * 3072 + dc);
        }
        __syncthreads();

        f32x4 s_acc[2][8] = {};
#pragma unroll
        for (int ks = 0; ks < 2; ++ks) {
            bf16x8 bk8[8];
#pragma unroll
            for (int tj = 0; tj < 8; ++tj)
                bk8[tj] = *(bf16x8*)(KV + (tj * 16 + l16) * 72 + ks * 32 + quad * 8);
#pragma unroll
            for (int ti = 0; ti < 2; ++ti)
#pragma unroll
                for (int tj = 0; tj < 8; ++tj)
                    s_acc[ti][tj] = mfma16(aq[ti][ks], bk8[tj], s_acc[ti][tj]);
        }

        float negj[8]; int jcol[8];
#pragma unroll
        for (int tj = 0; tj < 8; ++tj) {
            jcol[tj] = jb + tj * 16 + l16;
            negj[tj] = (mask[bs_off + jcol[tj]] != 0) ? NEGF : 0.f;
        }
        float tmax[2][4];
#pragma unroll
        for (int ti = 0; ti < 2; ++ti)
#pragma unroll
            for (int r = 0; r < 4; ++r) tmax[ti][r] = NEGF;
#pragma unroll
        for (int ti = 0; ti < 2; ++ti) {
            int irow_base = q0 + wave * 32 + ti * 16 + quad * 4;
#pragma unroll
            for (int tj = 0; tj < 8; ++tj)
#pragma unroll
                for (int r = 0; r < 4; ++r) {
                    int dj = jcol[tj] - (irow_base + r);
                    float sc = (dj >= -128 && dj <= 128) ? (s_acc[ti][tj][r] + negj[tj]) : NEGF;
                    s_acc[ti][tj][r] = sc;
                    tmax[ti][r] = fmaxf(tmax[ti][r], sc);
                }
        }
#pragma unroll
        for (int ti = 0; ti < 2; ++ti)
#pragma unroll
            for (int r = 0; r < 4; ++r)
#pragma unroll
                for (int dsh = 1; dsh < 16; dsh <<= 1)
                    tmax[ti][r] = fmaxf(tmax[ti][r], __shfl_xor(tmax[ti][r], dsh));

        float alpha[2][4], lsum[2][4];
#pragma unroll
        for (int ti = 0; ti < 2; ++ti)
#pragma unroll
            for (int r = 0; r < 4; ++r) {
                float mnew = fmaxf(m_run[ti][r], tmax[ti][r]);
                alpha[ti][r] = safe_exp(m_run[ti][r] - mnew);
                m_run[ti][r] = mnew;
                lsum[ti][r] = 0.f;
            }
#pragma unroll
        for (int ti = 0; ti < 2; ++ti)
#pragma unroll
            for (int tj = 0; tj < 8; ++tj)
#pragma unroll
                for (int r = 0; r < 4; ++r) {
                    float p = safe_exp(s_acc[ti][tj][r] - m_run[ti][r]);
                    lsum[ti][r] += p;
                    PsQ[(wave * 32 + ti * 16 + quad * 4 + r) * 136 + tj * 16 + l16] = f2b(p);
                }
#pragma unroll
        for (int ti = 0; ti < 2; ++ti)
#pragma unroll
            for (int r = 0; r < 4; ++r) {
#pragma unroll
                for (int dsh = 1; dsh < 16; dsh <<= 1) lsum[ti][r] += __shfl_xor(lsum[ti][r], dsh);
                l_run[ti][r] = l_run[ti][r] * alpha[ti][r] + lsum[ti][r];
            }
#pragma unroll
        for (int ti = 0; ti < 2; ++ti)
#pragma unroll
            for (int dj = 0; dj < 4; ++dj)
#pragma unroll
                for (int r = 0; r < 4; ++r) o_acc[ti][dj][r] *= alpha[ti][r];

        __syncthreads();
#pragma unroll
        for (int l = 0; l < 4; ++l) {
            int idx = l * 256 + t;
            int d = idx >> 4, kc = (idx & 15) * 8;
            *(bf16x8*)(KV + d * 136 + kc) =
                *(const bf16x8*)(Vt + ((size_t)(b * 16 + h) * 64 + d) * 2048 + jb + kc);
        }
        __syncthreads();
#pragma unroll
        for (int ks = 0; ks < 4; ++ks) {
            bf16x8 ap[2], bv8[4];
#pragma unroll
            for (int ti = 0; ti < 2; ++ti)
                ap[ti] = *(bf16x8*)(PsQ + (wave * 32 + ti * 16 + l16) * 136 + ks * 32 + quad * 8);
#pragma unroll
            for (int dj = 0; dj < 4; ++dj)
                bv8[dj] = *(bf16x8*)(KV + (dj * 16 + l16) * 136 + ks * 32 + quad * 8);
#pragma unroll
            for (int ti = 0; ti < 2; ++ti)
#pragma unroll
                for (int dj = 0; dj < 4; ++dj)
                    o_acc[ti][dj] = mfma16(ap[ti], bv8[dj], o_acc[ti][dj]);
        }
    }

#pragma unroll
    for (int ti = 0; ti < 2; ++ti) {
        int irow_base = q0 + wave * 32 + ti * 16 + quad * 4;
#pragma unroll
        for (int r = 0; r < 4; ++r) {
            int i = irow_base + r;
            float m2 = fmaxf(m_run[ti][r], s_g[ti][r]);
            float pg = safe_exp(s_g[ti][r] - m2);
            float al = safe_exp(m_run[ti][r] - m2);
            float l2 = l_run[ti][r] * al + pg;
            float invl = 1.f / fmaxf(l2, 1e-30f);
            float qm = (mask[bs_off + i] > 0) ? 0.f : 1.f;
#pragma unroll
            for (int dj = 0; dj < 4; ++dj) {
                int d = dj * 16 + l16;
                float val = (o_acc[ti][dj][r] * al + pg * gvf[d]) * invl * qm;
                attn[((size_t)(bs_off + i)) * 1024 + h * 64 + d] = f2b(val);
            }
        }
    }
}

// ---------------------------------------------------------------------------
// y = LN(x + attn) * g + b ; writes bf16 (GEMM input) AND fp32 (residual).
// ---------------------------------------------------------------------------
__global__ __launch_bounds__(256) void resid_ln(
    const float* __restrict__ x, const short* __restrict__ attn,
    const float* __restrict__ g, const float* __restrict__ be,
    short* __restrict__ yb, float* __restrict__ yf)
{
    int row = blockIdx.x, t = threadIdx.x;
    int lane = t & 63, wave = t >> 6;
    const size_t base = (size_t)row * 1024;
    float v[4]; float s = 0.f, s2 = 0.f;
#pragma unroll
    for (int i = 0; i < 4; ++i) {
        int c = i * 256 + t;
        float val = x[base + c] + b2f(attn[base + c]);
        v[i] = val; s += val; s2 += val * val;
    }
#pragma unroll
    for (int off = 32; off > 0; off >>= 1) { s += __shfl_xor(s, off); s2 += __shfl_xor(s2, off); }
    __shared__ float red[8];
    if (lane == 0) { red[wave] = s; red[4 + wave] = s2; }
    __syncthreads();
    s  = red[0] + red[1] + red[2] + red[3];
    s2 = red[4] + red[5] + red[6] + red[7];
    float mu  = s * (1.f / 1024.f);
    float var = s2 * (1.f / 1024.f) - mu * mu;
    float inv = rsqrtf(fmaxf(var, 0.f) + 1e-5f);
#pragma unroll
    for (int i = 0; i < 4; ++i) {
        int c = i * 256 + t;
        float o = (v[i] - mu) * inv * g[c] + be[c];
        yb[base + c] = f2b(o);
        yf[base + c] = o;
    }
}

// ---------------------------------------------------------------------------
// workspace layout, units = bf16 elements (2 B). total 47M units = 94 MB.
// ---------------------------------------------------------------------------
static constexpr size_t MEG      = 1048576;
static constexpr size_t OFF_WQKV = 0;            // 3M  (3072x1024 bf16)
static constexpr size_t OFF_W1T  = 3 * MEG;      // 4M
static constexpr size_t OFF_W2T  = 7 * MEG;      // 4M
static constexpr size_t OFF_XB   = 11 * MEG;     // 4M
static constexpr size_t OFF_QKV  = 15 * MEG;     // 12M (4096x3072 bf16)
static constexpr size_t OFF_VT   = 27 * MEG;     // 4M
static constexpr size_t OFF_ATT  = 31 * MEG;     // 4M
static constexpr size_t OFF_YN   = 35 * MEG;     // 4M (bf16)
static constexpr size_t OFF_YF   = 39 * MEG;     // 8M units = 4M fp32
static constexpr size_t OFF_H    = OFF_QKV;      // 16M, aliases QKV+VT (dead)

extern "C" void kernel_launch(void* const* d_in, const int* in_sizes, int n_in,
                              void* d_out, int out_size, void* d_ws, size_t ws_size,
                              hipStream_t stream) {
    (void)in_sizes; (void)n_in; (void)out_size; (void)ws_size;
    const float* x    = (const float*)d_in[0];
    const int*   mask = (const int*)  d_in[1];
    const float* wq   = (const float*)d_in[2];
    const float* bq   = (const float*)d_in[3];
    const float* wk   = (const float*)d_in[4];
    const float* bk   = (const float*)d_in[5];
    const float* wv   = (const float*)d_in[6];
    const float* bv   = (const float*)d_in[7];
    // d_in[8..13] (global-query branch) are provably dead for the output
    const float* lng  = (const float*)d_in[14];
    const float* lnb  = (const float*)d_in[15];
    const float* w1   = (const float*)d_in[16];
    const float* b1   = (const float*)d_in[17];
    const float* w2   = (const float*)d_in[18];
    const float* b2   = (const float*)d_in[19];
    short* ws  = (short*)d_ws;
    float* out = (float*)d_out;

    dim3 tb(32, 8);
    cvt_transpose_qkv<<<dim3(32, 32, 3), tb, 0, stream>>>(wq, wk, wv, ws + OFF_WQKV);
    cvt_transpose<<<dim3(128, 32), tb, 0, stream>>>(w1, ws + OFF_W1T, 1024, 4096);
    cvt_transpose<<<dim3(32, 128), tb, 0, stream>>>(w2, ws + OFF_W2T, 4096, 1024);
    cvt_f32_bf16<<<4096, 256, 0, stream>>>(x, ws + OFF_XB, 4194304);

    // QKV = x @ [wq|wk|wv] + [bq|bk|bv], Q-part scaled by 1/8
    gemm_bt<<<dim3(32, 24), 256, 0, stream>>>(ws + OFF_XB, ws + OFF_WQKV,
                                              bq, bk, bv, nullptr,
                                              ws + OFF_QKV, nullptr,
                                              4096, 3072, 1024, 0.125f, 1024, 0);
    transpose_v<<<dim3(64, 2, 32), tb, 0, stream>>>(ws + OFF_QKV, ws + OFF_VT);

    attn_kernel<<<512, 256, 53760, stream>>>(ws + OFF_QKV, ws + OFF_VT,
                                             mask, bk, bv, ws + OFF_ATT);

    resid_ln<<<4096, 256, 0, stream>>>(x, ws + OFF_ATT, lng, lnb,
                                       ws + OFF_YN, (float*)(ws + OFF_YF));

    // h = gelu(y@w1 + b1) ; out = y + h@w2 + b2
    gemm_bt<<<dim3(32, 32), 256, 0, stream>>>(ws + OFF_YN, ws + OFF_W1T,
                                              b1, b1, b1, nullptr,
                                              ws + OFF_H, nullptr,
                                              4096, 4096, 1024, 1.0f, 0, 1);
    gemm_bt<<<dim3(32, 8), 256, 0, stream>>>(ws + OFF_H, ws + OFF_W2T,
                                             b2, b2, b2, (const float*)(ws + OFF_YF),
                                             nullptr, out,
                                             4096, 1024, 4096, 1.0f, 0, 2);
}

// Round 5
// 357.371 us; speedup vs baseline: 1.2596x; 1.1043x over previous
//
#include <hip/hip_runtime.h>

// ---------------------------------------------------------------------------
// HFLongFormerSelfAttentionBlock — MI355X implementation (round 5)
//
// I/O fp32; internal bf16 MFMA, fp32 accumulation/epilogues.
// Round-5: MLP2 (M=4096,N=1024,K=4096) moved from 128x128 tiles (256 blocks,
// 1 block/CU -> latency-starved, MfmaUtil 13%) to 64x64 tiles (1024 blocks,
// 4 blocks/CU) with the same global_load_lds staging.
// ---------------------------------------------------------------------------

using bf16x8 = __attribute__((ext_vector_type(8))) short;
using bf16x4 = __attribute__((ext_vector_type(4))) short;
using f32x4  = __attribute__((ext_vector_type(4))) float;

__device__ __forceinline__ float b2f(short s) {
    return __uint_as_float(((unsigned int)(unsigned short)s) << 16);
}
__device__ __forceinline__ short f2b(float f) {
    unsigned int u = __float_as_uint(f);
    u += 0x7fffu + ((u >> 16) & 1u);   // round-to-nearest-even
    return (short)(u >> 16);
}
__device__ __forceinline__ f32x4 mfma16(bf16x8 a, bf16x8 b, f32x4 c) {
    return __builtin_amdgcn_mfma_f32_16x16x32_bf16(a, b, c, 0, 0, 0);
}
__device__ __forceinline__ float safe_exp(float x) {
    return expf((x <= 0.f) ? x : 0.f);
}
// async global->LDS, 16 B per lane; LDS dest = wave-uniform base + lane*16
__device__ __forceinline__ void load_lds16(const short* g, short* l) {
    __builtin_amdgcn_global_load_lds((const __attribute__((address_space(1))) void*)g,
                                     (__attribute__((address_space(3))) void*)l, 16, 0, 0);
}
#define NEGF (-3.0e38f)

// ---------------------------------------------------------------------------
// fp32 -> bf16 elementwise convert (n multiple of 1024). grid n/1024, 256 thr
// ---------------------------------------------------------------------------
__global__ void cvt_f32_bf16(const float* __restrict__ in, short* __restrict__ out, int n) {
    int i = (blockIdx.x * 256 + threadIdx.x) * 4;
    f32x4 v = *(const f32x4*)(in + i);
    bf16x4 o;
#pragma unroll
    for (int j = 0; j < 4; ++j) o[j] = f2b(v[j]);
    *(bf16x4*)(out + i) = o;
}

// ---------------------------------------------------------------------------
// fp32 in, bf16 transposed out: out[c][r] = in[r][c], in is R x C.
// grid (C/32, R/32), block (32,8)
// ---------------------------------------------------------------------------
__global__ void cvt_transpose(const float* __restrict__ in, short* __restrict__ out,
                              int R, int C) {
    __shared__ short tile[32][33];
    int bx = blockIdx.x * 32, by = blockIdx.y * 32;
    int tx = threadIdx.x, ty = threadIdx.y;
    for (int i = ty; i < 32; i += 8)
        tile[i][tx] = f2b(in[(size_t)(by + i) * C + bx + tx]);
    __syncthreads();
    for (int i = ty; i < 32; i += 8)
        out[(size_t)(bx + i) * R + by + tx] = tile[tx][i];
}

// wq/wk/wv (each 1024x1024 fp32) -> WQKVT (3072x1024 bf16, = [wq^T;wk^T;wv^T])
__global__ void cvt_transpose_qkv(const float* __restrict__ wq, const float* __restrict__ wk,
                                  const float* __restrict__ wv, short* __restrict__ out) {
    __shared__ short tile[32][33];
    const float* in = (blockIdx.z == 0) ? wq : (blockIdx.z == 1) ? wk : wv;
    short* dst = out + (size_t)blockIdx.z * 1024 * 1024;
    int bx = blockIdx.x * 32, by = blockIdx.y * 32;
    int tx = threadIdx.x, ty = threadIdx.y;
    for (int i = ty; i < 32; i += 8)
        tile[i][tx] = f2b(in[(size_t)(by + i) * 1024 + bx + tx]);
    __syncthreads();
    for (int i = ty; i < 32; i += 8)
        dst[(size_t)(bx + i) * 1024 + by + tx] = tile[tx][i];
}

// V columns of QKV (b,s,3072)[,2048+h*64+d] -> Vt (b,h,d,s).
__global__ void transpose_v(const short* __restrict__ QKV, short* __restrict__ Vt) {
    __shared__ short tile[32][33];
    int bh = blockIdx.z; int b = bh >> 4, h = bh & 15;
    int j0 = blockIdx.x * 32, d0 = blockIdx.y * 32;
    int tx = threadIdx.x, ty = threadIdx.y;
    const short* src = QKV + (size_t)b * 2048 * 3072 + 2048 + h * 64;
    for (int i = ty; i < 32; i += 8)
        tile[i][tx] = src[(size_t)(j0 + i) * 3072 + d0 + tx];
    __syncthreads();
    short* dst = Vt + ((size_t)bh * 64 + d0) * 2048 + j0;
    for (int i = ty; i < 32; i += 8)
        dst[(size_t)i * 2048 + tx] = tile[tx][i];
}

// ---------------------------------------------------------------------------
// GEMM 128x128 (m97 staging): acc = A(MxK) @ B, Bt = B^T (NxK), bf16 in.
// mode 0: C = bf16((acc+bias_sel)*scale_sel)  (QKV: per-1024-col bias select)
// mode 1: C = bf16(gelu(acc+bias))
// ---------------------------------------------------------------------------
__global__ __launch_bounds__(256, 2) void gemm_bt(
    const short* __restrict__ A, const short* __restrict__ Bt,
    const float* __restrict__ bias0, const float* __restrict__ bias1,
    const float* __restrict__ bias2,
    short* __restrict__ C,
    int M, int N, int K, float scale, int scale_cols, int mode)
{
    __shared__ short As[128 * 32];
    __shared__ short Bs[128 * 32];
    int m0 = blockIdx.x * 128, n0 = blockIdx.y * 128;
    int t = threadIdx.x;
    int wave = t >> 6, lane = t & 63, quad = lane >> 4, l16 = lane & 15;
    int wr = (wave >> 1) * 64, wc = (wave & 1) * 64;

    int ch0 = wave * 64 + lane;
    int ch1 = (4 + wave) * 64 + lane;
    int r0 = ch0 >> 2, kc0 = (ch0 & 3) * 8;
    int r1 = ch1 >> 2, kc1 = (ch1 & 3) * 8;
    const short* a0 = A  + (size_t)(m0 + r0) * K + kc0;
    const short* a1 = A  + (size_t)(m0 + r1) * K + kc1;
    const short* b0 = Bt + (size_t)(n0 + r0) * K + kc0;
    const short* b1 = Bt + (size_t)(n0 + r1) * K + kc1;
    short* lA0 = As + wave * 512;
    short* lA1 = As + (4 + wave) * 512;
    short* lB0 = Bs + wave * 512;
    short* lB1 = Bs + (4 + wave) * 512;

    f32x4 acc[4][4] = {};
    for (int k0 = 0; k0 < K; k0 += 32) {
        load_lds16(a0 + k0, lA0);
        load_lds16(a1 + k0, lA1);
        load_lds16(b0 + k0, lB0);
        load_lds16(b1 + k0, lB1);
        __syncthreads();
        bf16x8 af[4], bfr[4];
#pragma unroll
        for (int i = 0; i < 4; ++i)
            af[i] = *(bf16x8*)(As + (wr + i * 16 + l16) * 32 + quad * 8);
#pragma unroll
        for (int j = 0; j < 4; ++j)
            bfr[j] = *(bf16x8*)(Bs + (wc + j * 16 + l16) * 32 + quad * 8);
#pragma unroll
        for (int i = 0; i < 4; ++i)
#pragma unroll
            for (int j = 0; j < 4; ++j)
                acc[i][j] = mfma16(af[i], bfr[j], acc[i][j]);
        __syncthreads();
    }
#pragma unroll
    for (int j = 0; j < 4; ++j) {
        int col = n0 + wc + j * 16 + l16;
        int seg = col >> 10;
        const float* bp = (seg == 0) ? bias0 : (seg == 1) ? bias1 : bias2;
        float bs = bp[col & 1023];
        float sc = (col < scale_cols) ? scale : 1.0f;
#pragma unroll
        for (int i = 0; i < 4; ++i) {
#pragma unroll
            for (int r = 0; r < 4; ++r) {
                int row = m0 + wr + i * 16 + quad * 4 + r;
                float v = acc[i][j][r] + bs;
                if (mode == 0) {
                    C[(size_t)row * N + col] = f2b(v * sc);
                } else {
                    v = 0.5f * v * (1.0f + erff(v * 0.70710678118f));
                    C[(size_t)row * N + col] = f2b(v);
                }
            }
        }
    }
}

// ---------------------------------------------------------------------------
// GEMM 64x64 (high block count, for low-N shapes): Cf = A@B + bias + resf
// (fp32 out). grid (M/64, N/64), 4 waves, each computing a 32x32 quadrant.
// LDS 2 x 4 KB; 1 global_load_lds per wave per buffer per K-step.
// ---------------------------------------------------------------------------
__global__ __launch_bounds__(256, 4) void gemm64_bt(
    const short* __restrict__ A, const short* __restrict__ Bt,
    const float* __restrict__ bias, const float* __restrict__ resf,
    float* __restrict__ Cf, int M, int N, int K)
{
    __shared__ short As[64 * 32];
    __shared__ short Bs[64 * 32];
    int m0 = blockIdx.x * 64, n0 = blockIdx.y * 64;
    int t = threadIdx.x;
    int wave = t >> 6, lane = t & 63, quad = lane >> 4, l16 = lane & 15;
    int wr = (wave >> 1) * 32, wc = (wave & 1) * 32;

    int ch = wave * 64 + lane;             // chunk: 16 B per lane
    int r0 = ch >> 2, kc0 = (ch & 3) * 8;
    const short* a0 = A  + (size_t)(m0 + r0) * K + kc0;
    const short* b0 = Bt + (size_t)(n0 + r0) * K + kc0;
    short* lA = As + wave * 512;
    short* lB = Bs + wave * 512;

    f32x4 acc[2][2] = {};
    for (int k0 = 0; k0 < K; k0 += 32) {
        load_lds16(a0 + k0, lA);
        load_lds16(b0 + k0, lB);
        __syncthreads();
        bf16x8 af[2], bfr[2];
#pragma unroll
        for (int i = 0; i < 2; ++i)
            af[i] = *(bf16x8*)(As + (wr + i * 16 + l16) * 32 + quad * 8);
#pragma unroll
        for (int j = 0; j < 2; ++j)
            bfr[j] = *(bf16x8*)(Bs + (wc + j * 16 + l16) * 32 + quad * 8);
#pragma unroll
        for (int i = 0; i < 2; ++i)
#pragma unroll
            for (int j = 0; j < 2; ++j)
                acc[i][j] = mfma16(af[i], bfr[j], acc[i][j]);
        __syncthreads();
    }
#pragma unroll
    for (int j = 0; j < 2; ++j) {
        int col = n0 + wc + j * 16 + l16;
        float bs = bias[col];
#pragma unroll
        for (int i = 0; i < 2; ++i) {
#pragma unroll
            for (int r = 0; r < 4; ++r) {
                int row = m0 + wr + i * 16 + quad * 4 + r;
                Cf[(size_t)row * N + col] = acc[i][j][r] + bs + resf[(size_t)row * N + col];
            }
        }
    }
}

// ---------------------------------------------------------------------------
// Windowed attention with global column (unchanged from round 4).
// ---------------------------------------------------------------------------
__global__ __launch_bounds__(256, 2) void attn_kernel(
    const short* __restrict__ QKV, const short* __restrict__ Vt,
    const int* __restrict__ mask,
    const float* __restrict__ bk, const float* __restrict__ bv,
    short* __restrict__ attn)
{
    extern __shared__ char smem[];
    short* PsQ = (short*)smem;
    short* KV  = (short*)(smem + 34816);
    float* gkf = (float*)(smem + 53248);
    float* gvf = (float*)(smem + 53504);

    int blk = blockIdx.x;
    int c = blk & 15, h = (blk >> 4) & 15, b = blk >> 8;
    int t = threadIdx.x;
    int wave = t >> 6, lane = t & 63, quad = lane >> 4, l16 = lane & 15;
    int q0 = c * 128;
    const int bs_off = b * 2048;
    const short* Q = QKV + h * 64;
    const short* K = QKV + 1024 + h * 64;

#pragma unroll
    for (int l = 0; l < 4; ++l) {
        int idx = l * 256 + t;
        int p = idx >> 3, dc = (idx & 7) * 8;
        *(bf16x8*)(PsQ + p * 72 + dc) =
            *(const bf16x8*)(Q + ((size_t)(bs_off + q0 + p)) * 3072 + dc);
    }
    if (t < 64) { gkf[t] = bk[h * 64 + t]; gvf[t] = bv[h * 64 + t]; }
    __syncthreads();

    bf16x8 aq[2][2];
#pragma unroll
    for (int ti = 0; ti < 2; ++ti)
#pragma unroll
        for (int ks = 0; ks < 2; ++ks)
            aq[ti][ks] = *(bf16x8*)(PsQ + (wave * 32 + ti * 16 + l16) * 72 + ks * 32 + quad * 8);

    float s_g[2][4];
#pragma unroll
    for (int ti = 0; ti < 2; ++ti)
#pragma unroll
        for (int r = 0; r < 4; ++r) {
            int row = wave * 32 + ti * 16 + quad * 4 + r;
            float part = 0.f;
#pragma unroll
            for (int dd = 0; dd < 4; ++dd) {
                int d = l16 * 4 + dd;
                part += b2f(PsQ[row * 72 + d]) * gkf[d];
            }
#pragma unroll
            for (int dsh = 1; dsh < 16; dsh <<= 1) part += __shfl_xor(part, dsh);
            s_g[ti][r] = part;
        }

    f32x4 o_acc[2][4] = {};
    float m_run[2][4], l_run[2][4];
#pragma unroll
    for (int ti = 0; ti < 2; ++ti)
#pragma unroll
        for (int r = 0; r < 4; ++r) { m_run[ti][r] = NEGF; l_run[ti][r] = 0.f; }

    int kt_beg = (q0 == 0) ? 1 : 0;
    int kt_end = (q0 + 256 > 2048) ? 2 : 3;
    for (int kt = kt_beg; kt < kt_end; ++kt) {
        int jb = q0 + (kt - 1) * 128;
        __syncthreads();
#pragma unroll
        for (int l = 0; l < 4; ++l) {
            int idx = l * 256 + t;
            int p = idx >> 3, dc = (idx & 7) * 8;
            *(bf16x8*)(KV + p * 72 + dc) =
                *(const bf16x8*)(K + ((size_t)(bs_off + jb + p)) * 3072 + dc);
        }
        __syncthreads();

        f32x4 s_acc[2][8] = {};
#pragma unroll
        for (int ks = 0; ks < 2; ++ks) {
            bf16x8 bk8[8];
#pragma unroll
            for (int tj = 0; tj < 8; ++tj)
                bk8[tj] = *(bf16x8*)(KV + (tj * 16 + l16) * 72 + ks * 32 + quad * 8);
#pragma unroll
            for (int ti = 0; ti < 2; ++ti)
#pragma unroll
                for (int tj = 0; tj < 8; ++tj)
                    s_acc[ti][tj] = mfma16(aq[ti][ks], bk8[tj], s_acc[ti][tj]);
        }

        float negj[8]; int jcol[8];
#pragma unroll
        for (int tj = 0; tj < 8; ++tj) {
            jcol[tj] = jb + tj * 16 + l16;
            negj[tj] = (mask[bs_off + jcol[tj]] != 0) ? NEGF : 0.f;
        }
        float tmax[2][4];
#pragma unroll
        for (int ti = 0; ti < 2; ++ti)
#pragma unroll
            for (int r = 0; r < 4; ++r) tmax[ti][r] = NEGF;
#pragma unroll
        for (int ti = 0; ti < 2; ++ti) {
            int irow_base = q0 + wave * 32 + ti * 16 + quad * 4;
#pragma unroll
            for (int tj = 0; tj < 8; ++tj)
#pragma unroll
                for (int r = 0; r < 4; ++r) {
                    int dj = jcol[tj] - (irow_base + r);
                    float sc = (dj >= -128 && dj <= 128) ? (s_acc[ti][tj][r] + negj[tj]) : NEGF;
                    s_acc[ti][tj][r] = sc;
                    tmax[ti][r] = fmaxf(tmax[ti][r], sc);
                }
        }
#pragma unroll
        for (int ti = 0; ti < 2; ++ti)
#pragma unroll
            for (int r = 0; r < 4; ++r)
#pragma unroll
                for (int dsh = 1; dsh < 16; dsh <<= 1)
                    tmax[ti][r] = fmaxf(tmax[ti][r], __shfl_xor(tmax[ti][r], dsh));

        float alpha[2][4], lsum[2][4];
#pragma unroll
        for (int ti = 0; ti < 2; ++ti)
#pragma unroll
            for (int r = 0; r < 4; ++r) {
                float mnew = fmaxf(m_run[ti][r], tmax[ti][r]);
                alpha[ti][r] = safe_exp(m_run[ti][r] - mnew);
                m_run[ti][r] = mnew;
                lsum[ti][r] = 0.f;
            }
#pragma unroll
        for (int ti = 0; ti < 2; ++ti)
#pragma unroll
            for (int tj = 0; tj < 8; ++tj)
#pragma unroll
                for (int r = 0; r < 4; ++r) {
                    float p = safe_exp(s_acc[ti][tj][r] - m_run[ti][r]);
                    lsum[ti][r] += p;
                    PsQ[(wave * 32 + ti * 16 + quad * 4 + r) * 136 + tj * 16 + l16] = f2b(p);
                }
#pragma unroll
        for (int ti = 0; ti < 2; ++ti)
#pragma unroll
            for (int r = 0; r < 4; ++r) {
#pragma unroll
                for (int dsh = 1; dsh < 16; dsh <<= 1) lsum[ti][r] += __shfl_xor(lsum[ti][r], dsh);
                l_run[ti][r] = l_run[ti][r] * alpha[ti][r] + lsum[ti][r];
            }
#pragma unroll
        for (int ti = 0; ti < 2; ++ti)
#pragma unroll
            for (int dj = 0; dj < 4; ++dj)
#pragma unroll
                for (int r = 0; r < 4; ++r) o_acc[ti][dj][r] *= alpha[ti][r];

        __syncthreads();
#pragma unroll
        for (int l = 0; l < 4; ++l) {
            int idx = l * 256 + t;
            int d = idx >> 4, kc = (idx & 15) * 8;
            *(bf16x8*)(KV + d * 136 + kc) =
                *(const bf16x8*)(Vt + ((size_t)(b * 16 + h) * 64 + d) * 2048 + jb + kc);
        }
        __syncthreads();
#pragma unroll
        for (int ks = 0; ks < 4; ++ks) {
            bf16x8 ap[2], bv8[4];
#pragma unroll
            for (int ti = 0; ti < 2; ++ti)
                ap[ti] = *(bf16x8*)(PsQ + (wave * 32 + ti * 16 + l16) * 136 + ks * 32 + quad * 8);
#pragma unroll
            for (int dj = 0; dj < 4; ++dj)
                bv8[dj] = *(bf16x8*)(KV + (dj * 16 + l16) * 136 + ks * 32 + quad * 8);
#pragma unroll
            for (int ti = 0; ti < 2; ++ti)
#pragma unroll
                for (int dj = 0; dj < 4; ++dj)
                    o_acc[ti][dj] = mfma16(ap[ti], bv8[dj], o_acc[ti][dj]);
        }
    }

#pragma unroll
    for (int ti = 0; ti < 2; ++ti) {
        int irow_base = q0 + wave * 32 + ti * 16 + quad * 4;
#pragma unroll
        for (int r = 0; r < 4; ++r) {
            int i = irow_base + r;
            float m2 = fmaxf(m_run[ti][r], s_g[ti][r]);
            float pg = safe_exp(s_g[ti][r] - m2);
            float al = safe_exp(m_run[ti][r] - m2);
            float l2 = l_run[ti][r] * al + pg;
            float invl = 1.f / fmaxf(l2, 1e-30f);
            float qm = (mask[bs_off + i] > 0) ? 0.f : 1.f;
#pragma unroll
            for (int dj = 0; dj < 4; ++dj) {
                int d = dj * 16 + l16;
                float val = (o_acc[ti][dj][r] * al + pg * gvf[d]) * invl * qm;
                attn[((size_t)(bs_off + i)) * 1024 + h * 64 + d] = f2b(val);
            }
        }
    }
}

// ---------------------------------------------------------------------------
// y = LN(x + attn) * g + b ; writes bf16 (GEMM input) AND fp32 (residual).
// ---------------------------------------------------------------------------
__global__ __launch_bounds__(256) void resid_ln(
    const float* __restrict__ x, const short* __restrict__ attn,
    const float* __restrict__ g, const float* __restrict__ be,
    short* __restrict__ yb, float* __restrict__ yf)
{
    int row = blockIdx.x, t = threadIdx.x;
    int lane = t & 63, wave = t >> 6;
    const size_t base = (size_t)row * 1024;
    float v[4]; float s = 0.f, s2 = 0.f;
#pragma unroll
    for (int i = 0; i < 4; ++i) {
        int c = i * 256 + t;
        float val = x[base + c] + b2f(attn[base + c]);
        v[i] = val; s += val; s2 += val * val;
    }
#pragma unroll
    for (int off = 32; off > 0; off >>= 1) { s += __shfl_xor(s, off); s2 += __shfl_xor(s2, off); }
    __shared__ float red[8];
    if (lane == 0) { red[wave] = s; red[4 + wave] = s2; }
    __syncthreads();
    s  = red[0] + red[1] + red[2] + red[3];
    s2 = red[4] + red[5] + red[6] + red[7];
    float mu  = s * (1.f / 1024.f);
    float var = s2 * (1.f / 1024.f) - mu * mu;
    float inv = rsqrtf(fmaxf(var, 0.f) + 1e-5f);
#pragma unroll
    for (int i = 0; i < 4; ++i) {
        int c = i * 256 + t;
        float o = (v[i] - mu) * inv * g[c] + be[c];
        yb[base + c] = f2b(o);
        yf[base + c] = o;
    }
}

// ---------------------------------------------------------------------------
// workspace layout, units = bf16 elements (2 B). total 47M units = 94 MB.
// ---------------------------------------------------------------------------
static constexpr size_t MEG      = 1048576;
static constexpr size_t OFF_WQKV = 0;            // 3M  (3072x1024 bf16)
static constexpr size_t OFF_W1T  = 3 * MEG;      // 4M
static constexpr size_t OFF_W2T  = 7 * MEG;      // 4M
static constexpr size_t OFF_XB   = 11 * MEG;     // 4M
static constexpr size_t OFF_QKV  = 15 * MEG;     // 12M (4096x3072 bf16)
static constexpr size_t OFF_VT   = 27 * MEG;     // 4M
static constexpr size_t OFF_ATT  = 31 * MEG;     // 4M
static constexpr size_t OFF_YN   = 35 * MEG;     // 4M (bf16)
static constexpr size_t OFF_YF   = 39 * MEG;     // 8M units = 4M fp32
static constexpr size_t OFF_H    = OFF_QKV;      // 16M, aliases QKV+VT (dead)

extern "C" void kernel_launch(void* const* d_in, const int* in_sizes, int n_in,
                              void* d_out, int out_size, void* d_ws, size_t ws_size,
                              hipStream_t stream) {
    (void)in_sizes; (void)n_in; (void)out_size; (void)ws_size;
    const float* x    = (const float*)d_in[0];
    const int*   mask = (const int*)  d_in[1];
    const float* wq   = (const float*)d_in[2];
    const float* bq   = (const float*)d_in[3];
    const float* wk   = (const float*)d_in[4];
    const float* bk   = (const float*)d_in[5];
    const float* wv   = (const float*)d_in[6];
    const float* bv   = (const float*)d_in[7];
    // d_in[8..13] (global-query branch) are provably dead for the output
    const float* lng  = (const float*)d_in[14];
    const float* lnb  = (const float*)d_in[15];
    const float* w1   = (const float*)d_in[16];
    const float* b1   = (const float*)d_in[17];
    const float* w2   = (const float*)d_in[18];
    const float* b2   = (const float*)d_in[19];
    short* ws  = (short*)d_ws;
    float* out = (float*)d_out;

    dim3 tb(32, 8);
    cvt_transpose_qkv<<<dim3(32, 32, 3), tb, 0, stream>>>(wq, wk, wv, ws + OFF_WQKV);
    cvt_transpose<<<dim3(128, 32), tb, 0, stream>>>(w1, ws + OFF_W1T, 1024, 4096);
    cvt_transpose<<<dim3(32, 128), tb, 0, stream>>>(w2, ws + OFF_W2T, 4096, 1024);
    cvt_f32_bf16<<<4096, 256, 0, stream>>>(x, ws + OFF_XB, 4194304);

    // QKV = x @ [wq|wk|wv] + [bq|bk|bv], Q-part scaled by 1/8
    gemm_bt<<<dim3(32, 24), 256, 0, stream>>>(ws + OFF_XB, ws + OFF_WQKV,
                                              bq, bk, bv,
                                              ws + OFF_QKV,
                                              4096, 3072, 1024, 0.125f, 1024, 0);
    transpose_v<<<dim3(64, 2, 32), tb, 0, stream>>>(ws + OFF_QKV, ws + OFF_VT);

    attn_kernel<<<512, 256, 53760, stream>>>(ws + OFF_QKV, ws + OFF_VT,
                                             mask, bk, bv, ws + OFF_ATT);

    resid_ln<<<4096, 256, 0, stream>>>(x, ws + OFF_ATT, lng, lnb,
                                       ws + OFF_YN, (float*)(ws + OFF_YF));

    // h = gelu(y@w1 + b1)
    gemm_bt<<<dim3(32, 32), 256, 0, stream>>>(ws + OFF_YN, ws + OFF_W1T,
                                              b1, b1, b1,
                                              ws + OFF_H,
                                              4096, 4096, 1024, 1.0f, 0, 1);
    // out = y + h@w2 + b2   (64x64 tiles: 1024 blocks = 4 blocks/CU)
    gemm64_bt<<<dim3(64, 16), 256, 0, stream>>>(ws + OFF_H, ws + OFF_W2T,
                                                b2, (const float*)(ws + OFF_YF),
                                                out, 4096, 1024, 4096);
}

// Round 6
// 334.704 us; speedup vs baseline: 1.3449x; 1.0677x over previous
//
#include <hip/hip_runtime.h>

// ---------------------------------------------------------------------------
// HFLongFormerSelfAttentionBlock — MI355X implementation (round 6)
//
// I/O fp32; internal bf16 MFMA, fp32 accumulation/epilogues.
// Round-6: BK=64 K-tiles (half the barriers), XOR-swizzled LDS k-chunks
// (breaks the 16-way bank conflict BK=64 would cause), V^T fused into the
// QKV GEMM epilogue (transpose_v dispatch removed), MLP1 bias indexing FIXED
// (was bp[col&1023] against a 4096-long bias since round 4).
// ---------------------------------------------------------------------------

using bf16x8 = __attribute__((ext_vector_type(8))) short;
using bf16x4 = __attribute__((ext_vector_type(4))) short;
using f32x4  = __attribute__((ext_vector_type(4))) float;

__device__ __forceinline__ float b2f(short s) {
    return __uint_as_float(((unsigned int)(unsigned short)s) << 16);
}
__device__ __forceinline__ short f2b(float f) {
    unsigned int u = __float_as_uint(f);
    u += 0x7fffu + ((u >> 16) & 1u);   // round-to-nearest-even
    return (short)(u >> 16);
}
__device__ __forceinline__ f32x4 mfma16(bf16x8 a, bf16x8 b, f32x4 c) {
    return __builtin_amdgcn_mfma_f32_16x16x32_bf16(a, b, c, 0, 0, 0);
}
__device__ __forceinline__ float safe_exp(float x) {
    return expf((x <= 0.f) ? x : 0.f);
}
// async global->LDS, 16 B per lane; LDS dest = wave-uniform base + lane*16
__device__ __forceinline__ void load_lds16(const short* g, short* l) {
    __builtin_amdgcn_global_load_lds((const __attribute__((address_space(1))) void*)g,
                                     (__attribute__((address_space(3))) void*)l, 16, 0, 0);
}
#define NEGF (-3.0e38f)

// ---------------------------------------------------------------------------
// fp32 -> bf16 elementwise convert (n multiple of 1024). grid n/1024, 256 thr
// ---------------------------------------------------------------------------
__global__ void cvt_f32_bf16(const float* __restrict__ in, short* __restrict__ out, int n) {
    int i = (blockIdx.x * 256 + threadIdx.x) * 4;
    f32x4 v = *(const f32x4*)(in + i);
    bf16x4 o;
#pragma unroll
    for (int j = 0; j < 4; ++j) o[j] = f2b(v[j]);
    *(bf16x4*)(out + i) = o;
}

// ---------------------------------------------------------------------------
// fp32 in, bf16 transposed out: out[c][r] = in[r][c], in is R x C.
// grid (C/32, R/32), block (32,8)
// ---------------------------------------------------------------------------
__global__ void cvt_transpose(const float* __restrict__ in, short* __restrict__ out,
                              int R, int C) {
    __shared__ short tile[32][33];
    int bx = blockIdx.x * 32, by = blockIdx.y * 32;
    int tx = threadIdx.x, ty = threadIdx.y;
    for (int i = ty; i < 32; i += 8)
        tile[i][tx] = f2b(in[(size_t)(by + i) * C + bx + tx]);
    __syncthreads();
    for (int i = ty; i < 32; i += 8)
        out[(size_t)(bx + i) * R + by + tx] = tile[tx][i];
}

// wq/wk/wv (each 1024x1024 fp32) -> WQKVT (3072x1024 bf16, = [wq^T;wk^T;wv^T])
__global__ void cvt_transpose_qkv(const float* __restrict__ wq, const float* __restrict__ wk,
                                  const float* __restrict__ wv, short* __restrict__ out) {
    __shared__ short tile[32][33];
    const float* in = (blockIdx.z == 0) ? wq : (blockIdx.z == 1) ? wk : wv;
    short* dst = out + (size_t)blockIdx.z * 1024 * 1024;
    int bx = blockIdx.x * 32, by = blockIdx.y * 32;
    int tx = threadIdx.x, ty = threadIdx.y;
    for (int i = ty; i < 32; i += 8)
        tile[i][tx] = f2b(in[(size_t)(by + i) * 1024 + bx + tx]);
    __syncthreads();
    for (int i = ty; i < 32; i += 8)
        dst[(size_t)(bx + i) * 1024 + by + tx] = tile[tx][i];
}

// ---------------------------------------------------------------------------
// GEMM 128x128, BK=64, XOR-swizzled LDS k-chunks.
// LDS layout: L[row][slot] = G[row][slot ^ (row&7)]  (slot/chunk = 8 shorts).
// Staging lane i of chunk c: row = c*8 + (i>>3), global k-chunk (i&7)^(i>>3).
// Frag read (row, k-chunk t): LDS addr = row*64 + (t ^ (row&7))*8 shorts.
// mode 0: QKV — bias bq/bk/bv by col segment, Q scaled, V written to Vt(b,h,d,s)
// mode 1: C = bf16(gelu(acc + bias0[col]))
// ---------------------------------------------------------------------------
__global__ __launch_bounds__(256, 3) void gemm_bt(
    const short* __restrict__ A, const short* __restrict__ Bt,
    const float* __restrict__ bias0, const float* __restrict__ bias1,
    const float* __restrict__ bias2,
    short* __restrict__ C, short* __restrict__ Vt,
    int M, int N, int K, float scale, int mode)
{
    __shared__ short As[128 * 64];
    __shared__ short Bs[128 * 64];
    int m0 = blockIdx.x * 128, n0 = blockIdx.y * 128;
    int t = threadIdx.x;
    int wave = t >> 6, lane = t & 63, quad = lane >> 4, l16 = lane & 15;
    int wr = (wave >> 1) * 64, wc = (wave & 1) * 64;

    // staging pointers: 4 chunks per wave per buffer
    const short* ap[4]; const short* bp[4]; short* la[4]; short* lb[4];
    int gk = (((lane & 7) ^ (lane >> 3)) * 8);
#pragma unroll
    for (int l = 0; l < 4; ++l) {
        int c = wave * 4 + l;
        int row = c * 8 + (lane >> 3);
        ap[l] = A  + (size_t)(m0 + row) * K + gk;
        bp[l] = Bt + (size_t)(n0 + row) * K + gk;
        la[l] = As + c * 512;
        lb[l] = Bs + c * 512;
    }
    int sw = l16 & 7;   // frag-read swizzle key

    f32x4 acc[4][4] = {};
    for (int k0 = 0; k0 < K; k0 += 64) {
#pragma unroll
        for (int l = 0; l < 4; ++l) { load_lds16(ap[l] + k0, la[l]); load_lds16(bp[l] + k0, lb[l]); }
        __syncthreads();
#pragma unroll
        for (int ks = 0; ks < 2; ++ks) {
            int slot = ((ks * 4 + quad) ^ sw) * 8;
            bf16x8 af[4], bfr[4];
#pragma unroll
            for (int i = 0; i < 4; ++i)
                af[i] = *(bf16x8*)(As + (wr + i * 16 + l16) * 64 + slot);
#pragma unroll
            for (int j = 0; j < 4; ++j)
                bfr[j] = *(bf16x8*)(Bs + (wc + j * 16 + l16) * 64 + slot);
#pragma unroll
            for (int i = 0; i < 4; ++i)
#pragma unroll
                for (int j = 0; j < 4; ++j)
                    acc[i][j] = mfma16(af[i], bfr[j], acc[i][j]);
        }
        __syncthreads();
    }

#pragma unroll
    for (int j = 0; j < 4; ++j) {
        int col = n0 + wc + j * 16 + l16;
        if (mode == 1) {
            float bs = bias0[col];
#pragma unroll
            for (int i = 0; i < 4; ++i) {
#pragma unroll
                for (int r = 0; r < 4; ++r) {
                    int row = m0 + wr + i * 16 + quad * 4 + r;
                    float v = acc[i][j][r] + bs;
                    v = 0.5f * v * (1.0f + erff(v * 0.70710678118f));
                    C[(size_t)row * N + col] = f2b(v);
                }
            }
        } else {
            int seg = col >> 10;
            const float* bpt = (seg == 0) ? bias0 : (seg == 1) ? bias1 : bias2;
            float bs = bpt[col & 1023];
            if (seg < 2) {
                float sc = (seg == 0) ? scale : 1.0f;
#pragma unroll
                for (int i = 0; i < 4; ++i)
#pragma unroll
                    for (int r = 0; r < 4; ++r) {
                        int row = m0 + wr + i * 16 + quad * 4 + r;
                        C[(size_t)row * N + col] = f2b((acc[i][j][r] + bs) * sc);
                    }
            } else {
                // V part -> Vt (b, h, d, s), 4 consecutive s per thread
                int h = (col >> 6) & 15, d = col & 63;
#pragma unroll
                for (int i = 0; i < 4; ++i) {
                    int row0 = m0 + wr + i * 16 + quad * 4;
                    int bb = row0 >> 11, s0 = row0 & 2047;
                    bf16x4 vv;
#pragma unroll
                    for (int r = 0; r < 4; ++r) vv[r] = f2b(acc[i][j][r] + bs);
                    *(bf16x4*)(Vt + (((size_t)(bb * 16 + h)) * 64 + d) * 2048 + s0) = vv;
                }
            }
        }
    }
}

// ---------------------------------------------------------------------------
// GEMM 64x64, BK=64, same swizzle: Cf = A@B + bias + resf (fp32 out).
// grid (M/64, N/64); 4 waves, each a 32x32 quadrant. LDS 2 x 8 KB.
// ---------------------------------------------------------------------------
__global__ __launch_bounds__(256, 4) void gemm64_bt(
    const short* __restrict__ A, const short* __restrict__ Bt,
    const float* __restrict__ bias, const float* __restrict__ resf,
    float* __restrict__ Cf, int M, int N, int K)
{
    __shared__ short As[64 * 64];
    __shared__ short Bs[64 * 64];
    int m0 = blockIdx.x * 64, n0 = blockIdx.y * 64;
    int t = threadIdx.x;
    int wave = t >> 6, lane = t & 63, quad = lane >> 4, l16 = lane & 15;
    int wr = (wave >> 1) * 32, wc = (wave & 1) * 32;

    const short* ap[2]; const short* bp[2]; short* la[2]; short* lb[2];
    int gk = (((lane & 7) ^ (lane >> 3)) * 8);
#pragma unroll
    for (int l = 0; l < 2; ++l) {
        int c = wave * 2 + l;
        int row = c * 8 + (lane >> 3);
        ap[l] = A  + (size_t)(m0 + row) * K + gk;
        bp[l] = Bt + (size_t)(n0 + row) * K + gk;
        la[l] = As + c * 512;
        lb[l] = Bs + c * 512;
    }
    int sw = l16 & 7;

    f32x4 acc[2][2] = {};
    for (int k0 = 0; k0 < K; k0 += 64) {
#pragma unroll
        for (int l = 0; l < 2; ++l) { load_lds16(ap[l] + k0, la[l]); load_lds16(bp[l] + k0, lb[l]); }
        __syncthreads();
#pragma unroll
        for (int ks = 0; ks < 2; ++ks) {
            int slot = ((ks * 4 + quad) ^ sw) * 8;
            bf16x8 af[2], bfr[2];
#pragma unroll
            for (int i = 0; i < 2; ++i)
                af[i] = *(bf16x8*)(As + (wr + i * 16 + l16) * 64 + slot);
#pragma unroll
            for (int j = 0; j < 2; ++j)
                bfr[j] = *(bf16x8*)(Bs + (wc + j * 16 + l16) * 64 + slot);
#pragma unroll
            for (int i = 0; i < 2; ++i)
#pragma unroll
                for (int j = 0; j < 2; ++j)
                    acc[i][j] = mfma16(af[i], bfr[j], acc[i][j]);
        }
        __syncthreads();
    }
#pragma unroll
    for (int j = 0; j < 2; ++j) {
        int col = n0 + wc + j * 16 + l16;
        float bs = bias[col];
#pragma unroll
        for (int i = 0; i < 2; ++i) {
#pragma unroll
            for (int r = 0; r < 4; ++r) {
                int row = m0 + wr + i * 16 + quad * 4 + r;
                Cf[(size_t)row * N + col] = acc[i][j][r] + bs + resf[(size_t)row * N + col];
            }
        }
    }
}

// ---------------------------------------------------------------------------
// Windowed attention with global column (structure unchanged since round 4).
// ---------------------------------------------------------------------------
__global__ __launch_bounds__(256, 2) void attn_kernel(
    const short* __restrict__ QKV, const short* __restrict__ Vt,
    const int* __restrict__ mask,
    const float* __restrict__ bk, const float* __restrict__ bv,
    short* __restrict__ attn)
{
    extern __shared__ char smem[];
    short* PsQ = (short*)smem;
    short* KV  = (short*)(smem + 34816);
    float* gkf = (float*)(smem + 53248);
    float* gvf = (float*)(smem + 53504);

    int blk = blockIdx.x;
    int c = blk & 15, h = (blk >> 4) & 15, b = blk >> 8;
    int t = threadIdx.x;
    int wave = t >> 6, lane = t & 63, quad = lane >> 4, l16 = lane & 15;
    int q0 = c * 128;
    const int bs_off = b * 2048;
    const short* Q = QKV + h * 64;
    const short* K = QKV + 1024 + h * 64;

#pragma unroll
    for (int l = 0; l < 4; ++l) {
        int idx = l * 256 + t;
        int p = idx >> 3, dc = (idx & 7) * 8;
        *(bf16x8*)(PsQ + p * 72 + dc) =
            *(const bf16x8*)(Q + ((size_t)(bs_off + q0 + p)) * 3072 + dc);
    }
    if (t < 64) { gkf[t] = bk[h * 64 + t]; gvf[t] = bv[h * 64 + t]; }
    __syncthreads();

    bf16x8 aq[2][2];
#pragma unroll
    for (int ti = 0; ti < 2; ++ti)
#pragma unroll
        for (int ks = 0; ks < 2; ++ks)
            aq[ti][ks] = *(bf16x8*)(PsQ + (wave * 32 + ti * 16 + l16) * 72 + ks * 32 + quad * 8);

    float s_g[2][4];
#pragma unroll
    for (int ti = 0; ti < 2; ++ti)
#pragma unroll
        for (int r = 0; r < 4; ++r) {
            int row = wave * 32 + ti * 16 + quad * 4 + r;
            float part = 0.f;
#pragma unroll
            for (int dd = 0; dd < 4; ++dd) {
                int d = l16 * 4 + dd;
                part += b2f(PsQ[row * 72 + d]) * gkf[d];
            }
#pragma unroll
            for (int dsh = 1; dsh < 16; dsh <<= 1) part += __shfl_xor(part, dsh);
            s_g[ti][r] = part;
        }

    f32x4 o_acc[2][4] = {};
    float m_run[2][4], l_run[2][4];
#pragma unroll
    for (int ti = 0; ti < 2; ++ti)
#pragma unroll
        for (int r = 0; r < 4; ++r) { m_run[ti][r] = NEGF; l_run[ti][r] = 0.f; }

    int kt_beg = (q0 == 0) ? 1 : 0;
    int kt_end = (q0 + 256 > 2048) ? 2 : 3;
    for (int kt = kt_beg; kt < kt_end; ++kt) {
        int jb = q0 + (kt - 1) * 128;
        __syncthreads();
#pragma unroll
        for (int l = 0; l < 4; ++l) {
            int idx = l * 256 + t;
            int p = idx >> 3, dc = (idx & 7) * 8;
            *(bf16x8*)(KV + p * 72 + dc) =
                *(const bf16x8*)(K + ((size_t)(bs_off + jb + p)) * 3072 + dc);
        }
        __syncthreads();

        f32x4 s_acc[2][8] = {};
#pragma unroll
        for (int ks = 0; ks < 2; ++ks) {
            bf16x8 bk8[8];
#pragma unroll
            for (int tj = 0; tj < 8; ++tj)
                bk8[tj] = *(bf16x8*)(KV + (tj * 16 + l16) * 72 + ks * 32 + quad * 8);
#pragma unroll
            for (int ti = 0; ti < 2; ++ti)
#pragma unroll
                for (int tj = 0; tj < 8; ++tj)
                    s_acc[ti][tj] = mfma16(aq[ti][ks], bk8[tj], s_acc[ti][tj]);
        }

        float negj[8]; int jcol[8];
#pragma unroll
        for (int tj = 0; tj < 8; ++tj) {
            jcol[tj] = jb + tj * 16 + l16;
            negj[tj] = (mask[bs_off + jcol[tj]] != 0) ? NEGF : 0.f;
        }
        float tmax[2][4];
#pragma unroll
        for (int ti = 0; ti < 2; ++ti)
#pragma unroll
            for (int r = 0; r < 4; ++r) tmax[ti][r] = NEGF;
#pragma unroll
        for (int ti = 0; ti < 2; ++ti) {
            int irow_base = q0 + wave * 32 + ti * 16 + quad * 4;
#pragma unroll
            for (int tj = 0; tj < 8; ++tj)
#pragma unroll
                for (int r = 0; r < 4; ++r) {
                    int dj = jcol[tj] - (irow_base + r);
                    float sc = (dj >= -128 && dj <= 128) ? (s_acc[ti][tj][r] + negj[tj]) : NEGF;
                    s_acc[ti][tj][r] = sc;
                    tmax[ti][r] = fmaxf(tmax[ti][r], sc);
                }
        }
#pragma unroll
        for (int ti = 0; ti < 2; ++ti)
#pragma unroll
            for (int r = 0; r < 4; ++r)
#pragma unroll
                for (int dsh = 1; dsh < 16; dsh <<= 1)
                    tmax[ti][r] = fmaxf(tmax[ti][r], __shfl_xor(tmax[ti][r], dsh));

        float alpha[2][4], lsum[2][4];
#pragma unroll
        for (int ti = 0; ti < 2; ++ti)
#pragma unroll
            for (int r = 0; r < 4; ++r) {
                float mnew = fmaxf(m_run[ti][r], tmax[ti][r]);
                alpha[ti][r] = safe_exp(m_run[ti][r] - mnew);
                m_run[ti][r] = mnew;
                lsum[ti][r] = 0.f;
            }
#pragma unroll
        for (int ti = 0; ti < 2; ++ti)
#pragma unroll
            for (int tj = 0; tj < 8; ++tj)
#pragma unroll
                for (int r = 0; r < 4; ++r) {
                    float p = safe_exp(s_acc[ti][tj][r] - m_run[ti][r]);
                    lsum[ti][r] += p;
                    PsQ[(wave * 32 + ti * 16 + quad * 4 + r) * 136 + tj * 16 + l16] = f2b(p);
                }
#pragma unroll
        for (int ti = 0; ti < 2; ++ti)
#pragma unroll
            for (int r = 0; r < 4; ++r) {
#pragma unroll
                for (int dsh = 1; dsh < 16; dsh <<= 1) lsum[ti][r] += __shfl_xor(lsum[ti][r], dsh);
                l_run[ti][r] = l_run[ti][r] * alpha[ti][r] + lsum[ti][r];
            }
#pragma unroll
        for (int ti = 0; ti < 2; ++ti)
#pragma unroll
            for (int dj = 0; dj < 4; ++dj)
#pragma unroll
                for (int r = 0; r < 4; ++r) o_acc[ti][dj][r] *= alpha[ti][r];

        __syncthreads();
#pragma unroll
        for (int l = 0; l < 4; ++l) {
            int idx = l * 256 + t;
            int d = idx >> 4, kc = (idx & 15) * 8;
            *(bf16x8*)(KV + d * 136 + kc) =
                *(const bf16x8*)(Vt + ((size_t)(b * 16 + h) * 64 + d) * 2048 + jb + kc);
        }
        __syncthreads();
#pragma unroll
        for (int ks = 0; ks < 4; ++ks) {
            bf16x8 ap[2], bv8[4];
#pragma unroll
            for (int ti = 0; ti < 2; ++ti)
                ap[ti] = *(bf16x8*)(PsQ + (wave * 32 + ti * 16 + l16) * 136 + ks * 32 + quad * 8);
#pragma unroll
            for (int dj = 0; dj < 4; ++dj)
                bv8[dj] = *(bf16x8*)(KV + (dj * 16 + l16) * 136 + ks * 32 + quad * 8);
#pragma unroll
            for (int ti = 0; ti < 2; ++ti)
#pragma unroll
                for (int dj = 0; dj < 4; ++dj)
                    o_acc[ti][dj] = mfma16(ap[ti], bv8[dj], o_acc[ti][dj]);
        }
    }

#pragma unroll
    for (int ti = 0; ti < 2; ++ti) {
        int irow_base = q0 + wave * 32 + ti * 16 + quad * 4;
#pragma unroll
        for (int r = 0; r < 4; ++r) {
            int i = irow_base + r;
            float m2 = fmaxf(m_run[ti][r], s_g[ti][r]);
            float pg = safe_exp(s_g[ti][r] - m2);
            float al = safe_exp(m_run[ti][r] - m2);
            float l2 = l_run[ti][r] * al + pg;
            float invl = 1.f / fmaxf(l2, 1e-30f);
            float qm = (mask[bs_off + i] > 0) ? 0.f : 1.f;
#pragma unroll
            for (int dj = 0; dj < 4; ++dj) {
                int d = dj * 16 + l16;
                float val = (o_acc[ti][dj][r] * al + pg * gvf[d]) * invl * qm;
                attn[((size_t)(bs_off + i)) * 1024 + h * 64 + d] = f2b(val);
            }
        }
    }
}

// ---------------------------------------------------------------------------
// y = LN(x + attn) * g + b ; writes bf16 (GEMM input) AND fp32 (residual).
// ---------------------------------------------------------------------------
__global__ __launch_bounds__(256) void resid_ln(
    const float* __restrict__ x, const short* __restrict__ attn,
    const float* __restrict__ g, const float* __restrict__ be,
    short* __restrict__ yb, float* __restrict__ yf)
{
    int row = blockIdx.x, t = threadIdx.x;
    int lane = t & 63, wave = t >> 6;
    const size_t base = (size_t)row * 1024;
    float v[4]; float s = 0.f, s2 = 0.f;
#pragma unroll
    for (int i = 0; i < 4; ++i) {
        int c = i * 256 + t;
        float val = x[base + c] + b2f(attn[base + c]);
        v[i] = val; s += val; s2 += val * val;
    }
#pragma unroll
    for (int off = 32; off > 0; off >>= 1) { s += __shfl_xor(s, off); s2 += __shfl_xor(s2, off); }
    __shared__ float red[8];
    if (lane == 0) { red[wave] = s; red[4 + wave] = s2; }
    __syncthreads();
    s  = red[0] + red[1] + red[2] + red[3];
    s2 = red[4] + red[5] + red[6] + red[7];
    float mu  = s * (1.f / 1024.f);
    float var = s2 * (1.f / 1024.f) - mu * mu;
    float inv = rsqrtf(fmaxf(var, 0.f) + 1e-5f);
#pragma unroll
    for (int i = 0; i < 4; ++i) {
        int c = i * 256 + t;
        float o = (v[i] - mu) * inv * g[c] + be[c];
        yb[base + c] = f2b(o);
        yf[base + c] = o;
    }
}

// ---------------------------------------------------------------------------
// workspace layout, units = bf16 elements (2 B). total 47M units = 94 MB.
// ---------------------------------------------------------------------------
static constexpr size_t MEG      = 1048576;
static constexpr size_t OFF_WQKV = 0;            // 3M  (3072x1024 bf16)
static constexpr size_t OFF_W1T  = 3 * MEG;      // 4M
static constexpr size_t OFF_W2T  = 7 * MEG;      // 4M
static constexpr size_t OFF_XB   = 11 * MEG;     // 4M
static constexpr size_t OFF_QKV  = 15 * MEG;     // 12M (4096x3072 bf16; V third unused)
static constexpr size_t OFF_VT   = 27 * MEG;     // 4M
static constexpr size_t OFF_ATT  = 31 * MEG;     // 4M
static constexpr size_t OFF_YN   = 35 * MEG;     // 4M (bf16)
static constexpr size_t OFF_YF   = 39 * MEG;     // 8M units = 4M fp32
static constexpr size_t OFF_H    = OFF_QKV;      // 16M, aliases QKV+VT (dead)

extern "C" void kernel_launch(void* const* d_in, const int* in_sizes, int n_in,
                              void* d_out, int out_size, void* d_ws, size_t ws_size,
                              hipStream_t stream) {
    (void)in_sizes; (void)n_in; (void)out_size; (void)ws_size;
    const float* x    = (const float*)d_in[0];
    const int*   mask = (const int*)  d_in[1];
    const float* wq   = (const float*)d_in[2];
    const float* bq   = (const float*)d_in[3];
    const float* wk   = (const float*)d_in[4];
    const float* bk   = (const float*)d_in[5];
    const float* wv   = (const float*)d_in[6];
    const float* bv   = (const float*)d_in[7];
    // d_in[8..13] (global-query branch) are provably dead for the output
    const float* lng  = (const float*)d_in[14];
    const float* lnb  = (const float*)d_in[15];
    const float* w1   = (const float*)d_in[16];
    const float* b1   = (const float*)d_in[17];
    const float* w2   = (const float*)d_in[18];
    const float* b2   = (const float*)d_in[19];
    short* ws  = (short*)d_ws;
    float* out = (float*)d_out;

    dim3 tb(32, 8);
    cvt_transpose_qkv<<<dim3(32, 32, 3), tb, 0, stream>>>(wq, wk, wv, ws + OFF_WQKV);
    cvt_transpose<<<dim3(128, 32), tb, 0, stream>>>(w1, ws + OFF_W1T, 1024, 4096);
    cvt_transpose<<<dim3(32, 128), tb, 0, stream>>>(w2, ws + OFF_W2T, 4096, 1024);
    cvt_f32_bf16<<<4096, 256, 0, stream>>>(x, ws + OFF_XB, 4194304);

    // QKV = x @ [wq|wk|wv] + [bq|bk|bv]; Q scaled 1/8; V written to Vt fused
    gemm_bt<<<dim3(32, 24), 256, 0, stream>>>(ws + OFF_XB, ws + OFF_WQKV,
                                              bq, bk, bv,
                                              ws + OFF_QKV, ws + OFF_VT,
                                              4096, 3072, 1024, 0.125f, 0);

    attn_kernel<<<512, 256, 53760, stream>>>(ws + OFF_QKV, ws + OFF_VT,
                                             mask, bk, bv, ws + OFF_ATT);

    resid_ln<<<4096, 256, 0, stream>>>(x, ws + OFF_ATT, lng, lnb,
                                       ws + OFF_YN, (float*)(ws + OFF_YF));

    // h = gelu(y@w1 + b1)
    gemm_bt<<<dim3(32, 32), 256, 0, stream>>>(ws + OFF_YN, ws + OFF_W1T,
                                              b1, nullptr, nullptr,
                                              ws + OFF_H, nullptr,
                                              4096, 4096, 1024, 1.0f, 1);
    // out = y + h@w2 + b2
    gemm64_bt<<<dim3(64, 16), 256, 0, stream>>>(ws + OFF_H, ws + OFF_W2T,
                                                b2, (const float*)(ws + OFF_YF),
                                                out, 4096, 1024, 4096);
}